// Round 3
// baseline (518.546 us; speedup 1.0000x reference)
//
#include <hip/hip_runtime.h>
#include <stdint.h>

#define B_ 16
#define S1_ 2048
#define S2_ 2048
#define H_ 512

typedef short short8 __attribute__((ext_vector_type(8)));
typedef float f32x4 __attribute__((ext_vector_type(4)));

__device__ __forceinline__ unsigned short f2bf(float f) {
  unsigned u = __builtin_bit_cast(unsigned, f);
  u += 0x7fffu + ((u >> 16) & 1u);          // round-to-nearest-even
  return (unsigned short)(u >> 16);
}
__device__ __forceinline__ float bf2f(unsigned short us) {
  return __builtin_bit_cast(float, (unsigned)us << 16);
}

__device__ __forceinline__ void gload_lds16(const void* g, void* l) {
  __builtin_amdgcn_global_load_lds((const __attribute__((address_space(1))) void*)g,
                                   (__attribute__((address_space(3))) void*)l,
                                   16, 0, 0);
}

// ---------------- prep: row l2-normalize fp32 -> bf16 ----------------
__global__ __launch_bounds__(256) void k_rownorm(const float* __restrict__ x,
                                                 unsigned short* __restrict__ y) {
  int row = blockIdx.x * 4 + (threadIdx.x >> 6);
  int l = threadIdx.x & 63;
  const f32x4* xr = (const f32x4*)(x + (size_t)row * H_) + l * 2;
  f32x4 a = xr[0], b = xr[1];
  float s = a[0]*a[0] + a[1]*a[1] + a[2]*a[2] + a[3]*a[3]
          + b[0]*b[0] + b[1]*b[1] + b[2]*b[2] + b[3]*b[3];
#pragma unroll
  for (int m = 1; m < 64; m <<= 1) s += __shfl_xor(s, m);
  float sc = 1.0f / fmaxf(sqrtf(s), 1e-12f);
  short8 o;
#pragma unroll
  for (int i = 0; i < 4; ++i) { o[i] = (short)f2bf(a[i] * sc); o[4 + i] = (short)f2bf(b[i] * sc); }
  *(short8*)(y + (size_t)row * H_ + l * 8) = o;
}

// ---------------- prep: transpose+cast weights W[R][C] -> WT[C][R] bf16 ----------------
__global__ __launch_bounds__(256) void k_tw(const float* __restrict__ Wm,
                                            unsigned short* __restrict__ WT,
                                            int lgR, int C) {
  int i = blockIdx.x * 256 + threadIdx.x;     // over C*R outputs
  int R = 1 << lgR;
  int n = i >> lgR, k = i & (R - 1);
  WT[i] = f2bf(Wm[(size_t)k * C + n]);
}

// ---------------- prep: vt[b][h][s] bf16 = transpose(text2[b][s][h]) ----------------
__global__ __launch_bounds__(256) void k_tvt(const float* __restrict__ t2,
                                             unsigned short* __restrict__ vt) {
  __shared__ unsigned short tile[64][72];
  int h0 = blockIdx.x * 64, s0 = blockIdx.y * 64, b = blockIdx.z;
  int t = threadIdx.x;
#pragma unroll
  for (int p = 0; p < 4; ++p) {
    int si = p * 16 + (t >> 4);
    int cj = (t & 15) * 4;
    f32x4 v = *(const f32x4*)(t2 + ((size_t)(b * S2_ + s0 + si)) * H_ + h0 + cj);
    tile[si][cj]     = f2bf(v[0]);
    tile[si][cj + 1] = f2bf(v[1]);
    tile[si][cj + 2] = f2bf(v[2]);
    tile[si][cj + 3] = f2bf(v[3]);
  }
  __syncthreads();
#pragma unroll
  for (int p = 0; p < 2; ++p) {
    int ho = p * 32 + (t >> 3);
    int sx = (t & 7) * 8;
    short8 o;
#pragma unroll
    for (int x = 0; x < 8; ++x) o[x] = (short)tile[sx + x][ho];
    *(short8*)(vt + ((size_t)(b * H_ + h0 + ho)) * S2_ + s0 + sx) = o;
  }
}

// ---------------- 256-wide bf16 MFMA GEMM, 8 waves, BK=64, dbuf LDS ----------------
// C[M][N] = A[M][K] @ BT[N][K]^T, tile 256 x BN, batched via blockIdx.z.
// Schedule: per K-tile, 4 phases {ds_read quadrant frags + MFMA}, with tile t+1's
// global_load_lds issued in phases 0-1 (covered by ~3 phases of MFMA before the
// end-of-iteration drain+barrier). One barrier per K-tile.
// MODE 0: FF1 relu(acc+bias) bf16 | MODE 1: FF2 acc+bias f32
// MODE 2: P=exp(acc-1)*mask bf16 + rowsum atomics | MODE 3: acc/lbuf[row] bf16
template <int BN, int MODE>
__global__ __launch_bounds__(512, 1) void k_gemm(
    const unsigned short* __restrict__ A, const unsigned short* __restrict__ BT,
    const float* __restrict__ bias, const int* __restrict__ mask,
    float* __restrict__ lbuf, void* __restrict__ out,
    int M, int N, int K, long sA, long sB, long sOut) {
  constexpr int WN = BN / 64;            // waves along N (4 or 2)
  constexpr int WPM = 256 / (8 / WN);    // rows per wave (128 or 64)
  constexpr int M_REP = WPM / 16;        // 8 or 4
  constexpr int MH = M_REP / 2;
  constexpr int NBJ = BN / 512 ? (BN / 8) / 8 : (BN / 8) / 8;  // B gloads/wave
  constexpr int ABYTES = 256 * 64 * 2;   // 32 KiB per A buffer
  constexpr int BBYTES = BN * 64 * 2;

  __shared__ unsigned short lA[2][256 * 64];
  __shared__ unsigned short lB[2][BN * 64];

  const int z = blockIdx.z;
  const unsigned short* Ab = A + (size_t)z * sA;
  const unsigned short* BTb = BT + (size_t)z * sB;
  const int w = threadIdx.x >> 6, l = threadIdx.x & 63;
  const int lr = l & 15, lk = l >> 4;
  const int m0 = blockIdx.y * 256, n0 = blockIdx.x * BN;
  const int wm = (w / WN) * WPM, wn = (w % WN) * 64;

  // per-lane swizzled staging source base (chunk c = j*8+w covers 8 rows)
  const int lrow = w * 8 + (l >> 3);
  const int lswz = ((l & 7) * 16) ^ (((l >> 3) & 7) << 4);
  const char* pAb = (const char*)Ab + ((size_t)(m0 + lrow) * K) * 2 + lswz;
  const char* pBb = (const char*)BTb + ((size_t)(n0 + lrow) * K) * 2 + lswz;
  const size_t rstep = (size_t)K * 128;  // 64 rows * K * 2B

  f32x4 acc[M_REP][4];
#pragma unroll
  for (int i = 0; i < M_REP; ++i)
#pragma unroll
    for (int j = 0; j < 4; ++j) acc[i][j] = (f32x4){0.f, 0.f, 0.f, 0.f};

  const int NT = K >> 6;

  // prologue: stage tile 0 -> buf 0
#pragma unroll
  for (int j = 0; j < 4; ++j)
    gload_lds16(pAb + j * rstep, (char*)lA + (j * 8 + w) * 1024);
#pragma unroll
  for (int j = 0; j < NBJ; ++j)
    gload_lds16(pBb + j * rstep, (char*)lB + (j * 8 + w) * 1024);
  asm volatile("s_waitcnt vmcnt(0)" ::: "memory");
  __syncthreads();

#pragma unroll 1
  for (int t = 0; t < NT; ++t) {
    const int cur = t & 1;
    const unsigned short* As = lA[cur];
    const unsigned short* Bs = lB[cur];
    char* dA = (char*)lA + (cur ^ 1) * ABYTES;
    char* dB = (char*)lB + (cur ^ 1) * BBYTES;
    const size_t kb = (size_t)(t + 1) * 128;
    const bool pf = (t + 1 < NT);

    short8 aL[MH][2], aH[MH][2], b0f[2][2], b1f[2][2];

    // ---- phase 0: issue A(t+1) staging; read aL, b0; MFMA q0
    if (pf) {
#pragma unroll
      for (int j = 0; j < 4; ++j)
        gload_lds16(pAb + j * rstep + kb, dA + (j * 8 + w) * 1024);
    }
#pragma unroll
    for (int mi = 0; mi < MH; ++mi)
#pragma unroll
      for (int s = 0; s < 2; ++s) {
        int row = wm + mi * 16 + lr;
        aL[mi][s] = *(const short8*)(As + row * 64 + ((s * 32 + lk * 8) ^ ((row & 7) << 3)));
      }
#pragma unroll
    for (int ni = 0; ni < 2; ++ni)
#pragma unroll
      for (int s = 0; s < 2; ++s) {
        int row = wn + ni * 16 + lr;
        b0f[ni][s] = *(const short8*)(Bs + row * 64 + ((s * 32 + lk * 8) ^ ((row & 7) << 3)));
      }
    __builtin_amdgcn_s_setprio(1);
#pragma unroll
    for (int mi = 0; mi < MH; ++mi)
#pragma unroll
      for (int ni = 0; ni < 2; ++ni)
#pragma unroll
        for (int s = 0; s < 2; ++s)
          acc[mi][ni] = __builtin_amdgcn_mfma_f32_16x16x32_bf16(aL[mi][s], b0f[ni][s], acc[mi][ni], 0, 0, 0);
    __builtin_amdgcn_s_setprio(0);

    // ---- phase 1: issue B(t+1) staging; read b1; MFMA q1
    if (pf) {
#pragma unroll
      for (int j = 0; j < NBJ; ++j)
        gload_lds16(pBb + j * rstep + kb, dB + (j * 8 + w) * 1024);
    }
#pragma unroll
    for (int ni = 0; ni < 2; ++ni)
#pragma unroll
      for (int s = 0; s < 2; ++s) {
        int row = wn + 32 + ni * 16 + lr;
        b1f[ni][s] = *(const short8*)(Bs + row * 64 + ((s * 32 + lk * 8) ^ ((row & 7) << 3)));
      }
    __builtin_amdgcn_s_setprio(1);
#pragma unroll
    for (int mi = 0; mi < MH; ++mi)
#pragma unroll
      for (int ni = 0; ni < 2; ++ni)
#pragma unroll
        for (int s = 0; s < 2; ++s)
          acc[mi][2 + ni] = __builtin_amdgcn_mfma_f32_16x16x32_bf16(aL[mi][s], b1f[ni][s], acc[mi][2 + ni], 0, 0, 0);
    __builtin_amdgcn_s_setprio(0);

    // ---- phase 2: read aH; MFMA q2
#pragma unroll
    for (int mi = 0; mi < MH; ++mi)
#pragma unroll
      for (int s = 0; s < 2; ++s) {
        int row = wm + (MH + mi) * 16 + lr;
        aH[mi][s] = *(const short8*)(As + row * 64 + ((s * 32 + lk * 8) ^ ((row & 7) << 3)));
      }
    __builtin_amdgcn_s_setprio(1);
#pragma unroll
    for (int mi = 0; mi < MH; ++mi)
#pragma unroll
      for (int ni = 0; ni < 2; ++ni)
#pragma unroll
        for (int s = 0; s < 2; ++s)
          acc[MH + mi][2 + ni] = __builtin_amdgcn_mfma_f32_16x16x32_bf16(aH[mi][s], b1f[ni][s], acc[MH + mi][2 + ni], 0, 0, 0);
    __builtin_amdgcn_s_setprio(0);

    // ---- phase 3: MFMA q3 (pure compute; staging loads completing underneath)
    __builtin_amdgcn_s_setprio(1);
#pragma unroll
    for (int mi = 0; mi < MH; ++mi)
#pragma unroll
      for (int ni = 0; ni < 2; ++ni)
#pragma unroll
        for (int s = 0; s < 2; ++s)
          acc[MH + mi][ni] = __builtin_amdgcn_mfma_f32_16x16x32_bf16(aH[mi][s], b0f[ni][s], acc[MH + mi][ni], 0, 0, 0);
    __builtin_amdgcn_s_setprio(0);

    asm volatile("s_waitcnt vmcnt(0)" ::: "memory");
    __syncthreads();
  }

  if (MODE == 2) {
    float rs[M_REP][4];
#pragma unroll
    for (int mi = 0; mi < M_REP; ++mi)
#pragma unroll
      for (int r = 0; r < 4; ++r) rs[mi][r] = 0.f;
#pragma unroll
    for (int mi = 0; mi < M_REP; ++mi)
#pragma unroll
      for (int ni = 0; ni < 4; ++ni) {
        int gn = n0 + wn + ni * 16 + lr;
        float mv = (mask[(size_t)z * N + gn] != 0) ? 1.0f : 0.0f;
#pragma unroll
        for (int r = 0; r < 4; ++r) {
          int gm = m0 + wm + mi * 16 + lk * 4 + r;
          float p = __expf(acc[mi][ni][r] - 1.0f) * mv;
          rs[mi][r] += p;
          ((unsigned short*)out)[(size_t)z * sOut + (size_t)gm * N + gn] = f2bf(p);
        }
      }
#pragma unroll
    for (int mi = 0; mi < M_REP; ++mi)
#pragma unroll
      for (int r = 0; r < 4; ++r) {
        float s = rs[mi][r];
        s += __shfl_xor(s, 1); s += __shfl_xor(s, 2); s += __shfl_xor(s, 4); s += __shfl_xor(s, 8);
        if (lr == 0) {
          int gm = m0 + wm + mi * 16 + lk * 4 + r;
          atomicAdd(&lbuf[(size_t)z * M + gm], s);
        }
      }
  } else if (MODE == 3) {
#pragma unroll
    for (int mi = 0; mi < M_REP; ++mi)
#pragma unroll
      for (int r = 0; r < 4; ++r) {
        int gm = m0 + wm + mi * 16 + lk * 4 + r;
        float rl = 1.0f / lbuf[(size_t)z * M + gm];
#pragma unroll
        for (int ni = 0; ni < 4; ++ni) {
          int gn = n0 + wn + ni * 16 + lr;
          ((unsigned short*)out)[(size_t)z * sOut + (size_t)gm * N + gn] = f2bf(acc[mi][ni][r] * rl);
        }
      }
  } else {
#pragma unroll
    for (int mi = 0; mi < M_REP; ++mi)
#pragma unroll
      for (int ni = 0; ni < 4; ++ni) {
        int gn = n0 + wn + ni * 16 + lr;
        float bs = bias[gn];
#pragma unroll
        for (int r = 0; r < 4; ++r) {
          int gm = m0 + wm + mi * 16 + lk * 4 + r;
          float v = acc[mi][ni][r] + bs;
          if (MODE == 0) v = fmaxf(v, 0.f);
          if (MODE == 0) ((unsigned short*)out)[(size_t)gm * N + gn] = f2bf(v);
          else           ((float*)out)[(size_t)gm * N + gn] = v;
        }
      }
  }
}

// ---------------- LN1: nattn = LN(O)*g+b (bf16), resid = nattn + text1 (f32) ----------------
__global__ __launch_bounds__(256) void k_ln1(const unsigned short* __restrict__ O,
                                             const float* __restrict__ text1,
                                             const float* __restrict__ g,
                                             const float* __restrict__ bvec,
                                             unsigned short* __restrict__ nattn,
                                             float* __restrict__ resid) {
  int row = blockIdx.x * 4 + (threadIdx.x >> 6);
  int l = threadIdx.x & 63;
  size_t base = (size_t)row * H_ + l * 8;
  short8 ov = *(const short8*)(O + base);
  float x[8];
#pragma unroll
  for (int i = 0; i < 8; ++i) x[i] = bf2f((unsigned short)ov[i]);
  float s = 0.f, q = 0.f;
#pragma unroll
  for (int i = 0; i < 8; ++i) { s += x[i]; q += x[i] * x[i]; }
#pragma unroll
  for (int m = 1; m < 64; m <<= 1) { s += __shfl_xor(s, m); q += __shfl_xor(q, m); }
  float mean = s * (1.f / 512.f);
  float var = q * (1.f / 512.f) - mean * mean;
  float rstd = rsqrtf(var + 1e-6f);
  f32x4 g0 = *(const f32x4*)(g + l * 8), g1v = *(const f32x4*)(g + l * 8 + 4);
  f32x4 b0 = *(const f32x4*)(bvec + l * 8), b1v = *(const f32x4*)(bvec + l * 8 + 4);
  f32x4 t0 = *(const f32x4*)(text1 + base), t1 = *(const f32x4*)(text1 + base + 4);
  short8 no;
  f32x4 r0, r1;
#pragma unroll
  for (int i = 0; i < 4; ++i) {
    float y0 = (x[i] - mean) * rstd * g0[i] + b0[i];
    float y1 = (x[4 + i] - mean) * rstd * g1v[i] + b1v[i];
    no[i] = (short)f2bf(y0); no[4 + i] = (short)f2bf(y1);
    r0[i] = y0 + t0[i]; r1[i] = y1 + t1[i];
  }
  *(short8*)(nattn + base) = no;
  *(f32x4*)(resid + base) = r0;
  *(f32x4*)(resid + base + 4) = r1;
}

// ---------------- LN2(ff) + resid -> out ----------------
__global__ __launch_bounds__(256) void k_ln2(const float* __restrict__ ff,
                                             const float* __restrict__ resid,
                                             const float* __restrict__ g2,
                                             const float* __restrict__ bb2,
                                             float* __restrict__ out) {
  int row = blockIdx.x * 4 + (threadIdx.x >> 6);
  int l = threadIdx.x & 63;
  size_t base = (size_t)row * H_ + l * 8;
  f32x4 x0 = *(const f32x4*)(ff + base);
  f32x4 x1 = *(const f32x4*)(ff + base + 4);
  float s = x0[0] + x0[1] + x0[2] + x0[3] + x1[0] + x1[1] + x1[2] + x1[3];
  float q = x0[0]*x0[0] + x0[1]*x0[1] + x0[2]*x0[2] + x0[3]*x0[3]
          + x1[0]*x1[0] + x1[1]*x1[1] + x1[2]*x1[2] + x1[3]*x1[3];
#pragma unroll
  for (int m = 1; m < 64; m <<= 1) { s += __shfl_xor(s, m); q += __shfl_xor(q, m); }
  float mean = s * (1.f / 512.f);
  float var = q * (1.f / 512.f) - mean * mean;
  float rstd = rsqrtf(var + 1e-6f);
  f32x4 g0 = *(const f32x4*)(g2 + l * 8), g1v = *(const f32x4*)(g2 + l * 8 + 4);
  f32x4 b0 = *(const f32x4*)(bb2 + l * 8), b1v = *(const f32x4*)(bb2 + l * 8 + 4);
  f32x4 r0 = *(const f32x4*)(resid + base), r1 = *(const f32x4*)(resid + base + 4);
  f32x4 o0, o1;
#pragma unroll
  for (int i = 0; i < 4; ++i) {
    o0[i] = (x0[i] - mean) * rstd * g0[i] + b0[i] + r0[i];
    o1[i] = (x1[i] - mean) * rstd * g1v[i] + b1v[i] + r1[i];
  }
  *(f32x4*)(out + base) = o0;
  *(f32x4*)(out + base + 4) = o1;
}

extern "C" void kernel_launch(void* const* d_in, const int* in_sizes, int n_in,
                              void* d_out, int out_size, void* d_ws, size_t ws_size,
                              hipStream_t stream) {
  const float* text1 = (const float*)d_in[0];
  const float* text2 = (const float*)d_in[1];
  // d_in[2] = text1_mask (unused by reference output)
  const int* mask2 = (const int*)d_in[3];
  const float* W1 = (const float*)d_in[4];
  const float* b1 = (const float*)d_in[5];
  const float* W2 = (const float*)d_in[6];
  const float* b2 = (const float*)d_in[7];
  const float* g1 = (const float*)d_in[8];
  const float* bb1 = (const float*)d_in[9];
  const float* g2 = (const float*)d_in[10];
  const float* bb2 = (const float*)d_in[11];

  const size_t MiB = 1024ull * 1024ull;
  char* ws = (char*)d_ws;
  unsigned short* W1T   = (unsigned short*)(ws + 0 * MiB);    // 1 MiB
  unsigned short* W2T   = (unsigned short*)(ws + 1 * MiB);    // 1 MiB
  float*          lbuf  = (float*)(ws + 2 * MiB);             // 128 KiB
  unsigned short* qn    = (unsigned short*)(ws + 4 * MiB);    // 32 MiB [4,36)
  unsigned short* kn    = (unsigned short*)(ws + 36 * MiB);   // 32 MiB [36,68)
  unsigned short* vt    = (unsigned short*)(ws + 68 * MiB);   // 32 MiB [68,100)
  unsigned short* P     = (unsigned short*)(ws + 100 * MiB);  // 64 MiB [100,164) (8-batch chunk)
  unsigned short* O     = (unsigned short*)(ws + 164 * MiB);  // 32 MiB [164,196)
  // aliases (phase-ordered, see lifetimes):
  unsigned short* nattn = (unsigned short*)(ws + 100 * MiB);  // 32 MiB over P (P dead after pass2)
  float*          resid = (float*)(ws + 4 * MiB);             // 64 MiB over qn+kn (dead after pass1)
  unsigned short* hbuf  = (unsigned short*)(ws + 132 * MiB);  // 64 MiB over P-rest + O (dead after LN1)
  float*          ff    = (float*)(ws + 68 * MiB);            // 64 MiB over vt + nattn (dead after FF1)
  float* outp = (float*)d_out;

  hipMemsetAsync(lbuf, 0, (size_t)B_ * S1_ * sizeof(float), stream);

  k_rownorm<<<dim3(B_ * S1_ / 4), 256, 0, stream>>>(text1, qn);
  k_rownorm<<<dim3(B_ * S2_ / 4), 256, 0, stream>>>(text2, kn);
  k_tw<<<dim3(512 * 1024 / 256), 256, 0, stream>>>(W1, W1T, 9, 1024);
  k_tw<<<dim3(512 * 1024 / 256), 256, 0, stream>>>(W2, W2T, 10, 512);
  k_tvt<<<dim3(H_ / 64, S2_ / 64, B_), 256, 0, stream>>>(text2, vt);

  for (int c = 0; c < 2; ++c) {
    const int c0 = c * 8;
    // pass1: P = exp(qn @ kn^T - 1) * mask, row sums -> lbuf
    k_gemm<256, 2><<<dim3(S2_ / 256, S1_ / 256, 8), 512, 0, stream>>>(
        qn + (size_t)c0 * S1_ * H_, kn + (size_t)c0 * S2_ * H_,
        nullptr, mask2 + (size_t)c0 * S2_, lbuf + (size_t)c0 * S1_, P,
        S1_, S2_, H_, (long)S1_ * H_, (long)S2_ * H_, (long)S1_ * S2_);
    // pass2: O = (P @ V) / l   (bf16)
    k_gemm<128, 3><<<dim3(H_ / 128, S1_ / 256, 8), 512, 0, stream>>>(
        P, vt + (size_t)c0 * H_ * S2_,
        nullptr, nullptr, lbuf + (size_t)c0 * S1_, O + (size_t)c0 * S1_ * H_,
        S1_, H_, S2_, (long)S1_ * S2_, (long)H_ * S2_, (long)S1_ * H_);
  }

  k_ln1<<<dim3(B_ * S1_ / 4), 256, 0, stream>>>(O, text1, g1, bb1, nattn, resid);
  k_gemm<256, 0><<<dim3(1024 / 256, 32768 / 256, 1), 512, 0, stream>>>(
      nattn, W1T, b1, nullptr, nullptr, hbuf, 32768, 1024, 512, 0, 0, 0);
  k_gemm<128, 1><<<dim3(512 / 128, 32768 / 256, 1), 512, 0, stream>>>(
      hbuf, W2T, b2, nullptr, nullptr, ff, 32768, 512, 1024, 0, 0, 0);
  k_ln2<<<dim3(32768 / 4), 256, 0, stream>>>(ff, resid, g2, bb2, outp);
}

// Round 5
// 442.738 us; speedup vs baseline: 1.1712x; 1.1712x over previous
//
#include <hip/hip_runtime.h>
#include <stdint.h>

#define B_ 16
#define S1_ 2048
#define S2_ 2048
#define H_ 512

typedef short short8 __attribute__((ext_vector_type(8)));
typedef float f32x4 __attribute__((ext_vector_type(4)));

__device__ __forceinline__ unsigned short f2bf(float f) {
  unsigned u = __builtin_bit_cast(unsigned, f);
  u += 0x7fffu + ((u >> 16) & 1u);          // round-to-nearest-even
  return (unsigned short)(u >> 16);
}
__device__ __forceinline__ float bf2f(unsigned short us) {
  return __builtin_bit_cast(float, (unsigned)us << 16);
}

__device__ __forceinline__ void gload_lds16(const void* g, void* l) {
  __builtin_amdgcn_global_load_lds((const __attribute__((address_space(1))) void*)g,
                                   (__attribute__((address_space(3))) void*)l,
                                   16, 0, 0);
}

// ---------------- prep: bf16 cast + reciprocal row-norm ----------------
__global__ __launch_bounds__(256) void k_cast(const float* __restrict__ x,
                                              unsigned short* __restrict__ y,
                                              float* __restrict__ rn) {
  int row = blockIdx.x * 4 + (threadIdx.x >> 6);
  int l = threadIdx.x & 63;
  const f32x4* xr = (const f32x4*)(x + (size_t)row * H_) + l * 2;
  f32x4 a = xr[0], b = xr[1];
  float s = a[0]*a[0] + a[1]*a[1] + a[2]*a[2] + a[3]*a[3]
          + b[0]*b[0] + b[1]*b[1] + b[2]*b[2] + b[3]*b[3];
#pragma unroll
  for (int m = 1; m < 64; m <<= 1) s += __shfl_xor(s, m);
  if (l == 0) rn[row] = 1.0f / fmaxf(sqrtf(s), 1e-12f);
  short8 o;
#pragma unroll
  for (int i = 0; i < 4; ++i) { o[i] = (short)f2bf(a[i]); o[4 + i] = (short)f2bf(b[i]); }
  *(short8*)(y + (size_t)row * H_ + l * 8) = o;
}

// ---------------- prep: transpose+cast weights W[R][C] -> WT[C][R] bf16 ----------------
__global__ __launch_bounds__(256) void k_tw(const float* __restrict__ Wm,
                                            unsigned short* __restrict__ WT,
                                            int lgR, int C) {
  int i = blockIdx.x * 256 + threadIdx.x;     // over C*R outputs
  int R = 1 << lgR;
  int n = i >> lgR, k = i & (R - 1);
  WT[i] = f2bf(Wm[(size_t)k * C + n]);
}

// ---------------- prep: vt[b][h][s] = transpose(kn[b][s][h]) (bf16 -> bf16) ----------------
__global__ __launch_bounds__(256) void k_tvt(const unsigned short* __restrict__ kn,
                                             unsigned short* __restrict__ vt) {
  __shared__ unsigned short tile[64][72];
  int h0 = blockIdx.x * 64, s0 = blockIdx.y * 64, b = blockIdx.z;
  int t = threadIdx.x;
#pragma unroll
  for (int p = 0; p < 2; ++p) {
    int si = p * 32 + (t >> 3);
    int cj = (t & 7) * 8;
    short8 v = *(const short8*)(kn + ((size_t)(b * S2_ + s0 + si)) * H_ + h0 + cj);
#pragma unroll
    for (int x = 0; x < 8; ++x) tile[si][cj + x] = (unsigned short)v[x];
  }
  __syncthreads();
#pragma unroll
  for (int p = 0; p < 2; ++p) {
    int ho = p * 32 + (t >> 3);
    int sx = (t & 7) * 8;
    short8 o;
#pragma unroll
    for (int x = 0; x < 8; ++x) o[x] = (short)tile[sx + x][ho];
    *(short8*)(vt + ((size_t)(b * H_ + h0 + ho)) * S2_ + s0 + sx) = o;
  }
}

// ---------------- bf16 MFMA GEMM: 128x128 tile, BK=64, 4 waves, dbuf LDS, 2 blk/CU ----
// C[M][N] = A[M][K] @ BT[N][K]^T, batched via blockIdx.z.
// 2-phase: stage tile t+1 into buf^1, compute tile t, one vmcnt(0)+barrier per tile.
// MODE 0: FF1 relu(acc+bias) bf16 | MODE 1: FF2 acc+bias f32
// MODE 2: P=exp(acc*rq[m]*rk[n]-1)*mask bf16 + rowsum atomics | MODE 3: acc/lbuf[row] bf16
template <int MODE>
__global__ __launch_bounds__(256, 2) void k_gemm(
    const unsigned short* __restrict__ A, const unsigned short* __restrict__ BT,
    const float* __restrict__ bias, const int* __restrict__ mask,
    const float* __restrict__ rq, const float* __restrict__ rk,
    float* __restrict__ lbuf, void* __restrict__ out,
    int M, int N, int K, long sA, long sB, long sOut) {
  __shared__ unsigned short lA[2][128 * 64];
  __shared__ unsigned short lB[2][128 * 64];
  const int z = blockIdx.z;
  const unsigned short* Ab = A + (size_t)z * sA;
  const unsigned short* BTb = BT + (size_t)z * sB;
  const int w = threadIdx.x >> 6, l = threadIdx.x & 63;
  const int lr = l & 15, lk = l >> 4;
  const int m0 = blockIdx.y * 128, n0 = blockIdx.x * 128;
  const int wm = (w >> 1) * 64, wn = (w & 1) * 64;

  // staging: chunk c=j*4+w covers rows 8c..8c+7; lane l covers row 8c+(l>>3),
  // 16 source bytes at col ((l&7)*16) ^ XOR-swizzle; LDS dest linear.
  const int srow = l >> 3;
  const int lswz = ((l & 7) * 16) ^ ((srow & 7) << 4);
  const char* pA = (const char*)Ab + ((size_t)(m0 + w * 8 + srow) * K) * 2 + lswz;
  const char* pB = (const char*)BTb + ((size_t)(n0 + w * 8 + srow) * K) * 2 + lswz;
  const size_t rstep = (size_t)K * 64;   // 32 rows * K * 2B

  f32x4 acc[4][4];
#pragma unroll
  for (int i = 0; i < 4; ++i)
#pragma unroll
    for (int j = 0; j < 4; ++j) acc[i][j] = (f32x4){0.f, 0.f, 0.f, 0.f};

  const int NT = K >> 6;

  // prologue: stage tile 0 -> buf 0
#pragma unroll
  for (int j = 0; j < 4; ++j) {
    gload_lds16(pA + j * rstep, (char*)lA[0] + (j * 4 + w) * 1024);
    gload_lds16(pB + j * rstep, (char*)lB[0] + (j * 4 + w) * 1024);
  }
  asm volatile("s_waitcnt vmcnt(0)" ::: "memory");
  __syncthreads();

#pragma unroll 1
  for (int t = 0; t < NT; ++t) {
    const int cur = t & 1;
    const unsigned short* As = lA[cur];
    const unsigned short* Bs = lB[cur];
    // issue next tile's staging first (covered by this tile's compute)
    if (t + 1 < NT) {
      const size_t kb = (size_t)(t + 1) * 128;
      char* dA = (char*)lA[cur ^ 1];
      char* dB = (char*)lB[cur ^ 1];
#pragma unroll
      for (int j = 0; j < 4; ++j) {
        gload_lds16(pA + j * rstep + kb, dA + (j * 4 + w) * 1024);
        gload_lds16(pB + j * rstep + kb, dB + (j * 4 + w) * 1024);
      }
    }
    // compute current tile
#pragma unroll
    for (int s = 0; s < 2; ++s) {
      short8 af[4], bf[4];
#pragma unroll
      for (int mi = 0; mi < 4; ++mi) {
        int row = wm + mi * 16 + lr;
        af[mi] = *(const short8*)(As + row * 64 + ((s * 32 + lk * 8) ^ ((row & 7) << 3)));
      }
#pragma unroll
      for (int ni = 0; ni < 4; ++ni) {
        int row = wn + ni * 16 + lr;
        bf[ni] = *(const short8*)(Bs + row * 64 + ((s * 32 + lk * 8) ^ ((row & 7) << 3)));
      }
#pragma unroll
      for (int mi = 0; mi < 4; ++mi)
#pragma unroll
        for (int ni = 0; ni < 4; ++ni)
          acc[mi][ni] = __builtin_amdgcn_mfma_f32_16x16x32_bf16(af[mi], bf[ni], acc[mi][ni], 0, 0, 0);
    }
    asm volatile("s_waitcnt vmcnt(0)" ::: "memory");
    __syncthreads();
  }

  if (MODE == 2) {
    float rqv[4][4], rkv[4], mv[4];
#pragma unroll
    for (int mi = 0; mi < 4; ++mi)
#pragma unroll
      for (int r = 0; r < 4; ++r)
        rqv[mi][r] = rq[(size_t)z * M + m0 + wm + mi * 16 + lk * 4 + r];
#pragma unroll
    for (int ni = 0; ni < 4; ++ni) {
      int gn = n0 + wn + ni * 16 + lr;
      rkv[ni] = rk[(size_t)z * N + gn];
      mv[ni] = (mask[(size_t)z * N + gn] != 0) ? 1.0f : 0.0f;
    }
    float rs[4][4];
#pragma unroll
    for (int mi = 0; mi < 4; ++mi)
#pragma unroll
      for (int r = 0; r < 4; ++r) rs[mi][r] = 0.f;
#pragma unroll
    for (int mi = 0; mi < 4; ++mi)
#pragma unroll
      for (int ni = 0; ni < 4; ++ni) {
        int gn = n0 + wn + ni * 16 + lr;
#pragma unroll
        for (int r = 0; r < 4; ++r) {
          int gm = m0 + wm + mi * 16 + lk * 4 + r;
          float p = __expf(acc[mi][ni][r] * rqv[mi][r] * rkv[ni] - 1.0f) * mv[ni];
          rs[mi][r] += p;
          ((unsigned short*)out)[(size_t)z * sOut + (size_t)gm * N + gn] = f2bf(p);
        }
      }
#pragma unroll
    for (int mi = 0; mi < 4; ++mi)
#pragma unroll
      for (int r = 0; r < 4; ++r) {
        float s = rs[mi][r];
        s += __shfl_xor(s, 1); s += __shfl_xor(s, 2); s += __shfl_xor(s, 4); s += __shfl_xor(s, 8);
        if (lr == 0) {
          int gm = m0 + wm + mi * 16 + lk * 4 + r;
          atomicAdd(&lbuf[(size_t)z * M + gm], s);
        }
      }
  } else if (MODE == 3) {
#pragma unroll
    for (int mi = 0; mi < 4; ++mi)
#pragma unroll
      for (int r = 0; r < 4; ++r) {
        int gm = m0 + wm + mi * 16 + lk * 4 + r;
        float rl = 1.0f / lbuf[(size_t)z * M + gm];
#pragma unroll
        for (int ni = 0; ni < 4; ++ni) {
          int gn = n0 + wn + ni * 16 + lr;
          ((unsigned short*)out)[(size_t)z * sOut + (size_t)gm * N + gn] = f2bf(acc[mi][ni][r] * rl);
        }
      }
  } else {
#pragma unroll
    for (int mi = 0; mi < 4; ++mi)
#pragma unroll
      for (int ni = 0; ni < 4; ++ni) {
        int gn = n0 + wn + ni * 16 + lr;
        float bs = bias[gn];
#pragma unroll
        for (int r = 0; r < 4; ++r) {
          int gm = m0 + wm + mi * 16 + lk * 4 + r;
          float v = acc[mi][ni][r] + bs;
          if (MODE == 0) v = fmaxf(v, 0.f);
          if (MODE == 0) ((unsigned short*)out)[(size_t)gm * N + gn] = f2bf(v);
          else           ((float*)out)[(size_t)gm * N + gn] = v;
        }
      }
  }
}

// ---------------- LN1: nattn = LN(O)*g+b (bf16) ----------------
__global__ __launch_bounds__(256) void k_ln1(const unsigned short* __restrict__ O,
                                             const float* __restrict__ g,
                                             const float* __restrict__ bvec,
                                             unsigned short* __restrict__ nattn) {
  int row = blockIdx.x * 4 + (threadIdx.x >> 6);
  int l = threadIdx.x & 63;
  size_t base = (size_t)row * H_ + l * 8;
  short8 ov = *(const short8*)(O + base);
  float x[8];
#pragma unroll
  for (int i = 0; i < 8; ++i) x[i] = bf2f((unsigned short)ov[i]);
  float s = 0.f, q = 0.f;
#pragma unroll
  for (int i = 0; i < 8; ++i) { s += x[i]; q += x[i] * x[i]; }
#pragma unroll
  for (int m = 1; m < 64; m <<= 1) { s += __shfl_xor(s, m); q += __shfl_xor(q, m); }
  float mean = s * (1.f / 512.f);
  float var = q * (1.f / 512.f) - mean * mean;
  float rstd = rsqrtf(var + 1e-6f);
  f32x4 g0 = *(const f32x4*)(g + l * 8), g1v = *(const f32x4*)(g + l * 8 + 4);
  f32x4 b0 = *(const f32x4*)(bvec + l * 8), b1v = *(const f32x4*)(bvec + l * 8 + 4);
  short8 no;
#pragma unroll
  for (int i = 0; i < 4; ++i) {
    no[i]     = (short)f2bf((x[i] - mean) * rstd * g0[i] + b0[i]);
    no[4 + i] = (short)f2bf((x[4 + i] - mean) * rstd * g1v[i] + b1v[i]);
  }
  *(short8*)(nattn + base) = no;
}

// ---------------- LN2(ff) + nattn + text1 -> out ----------------
__global__ __launch_bounds__(256) void k_ln2(const float* __restrict__ ff,
                                             const unsigned short* __restrict__ nattn,
                                             const float* __restrict__ text1,
                                             const float* __restrict__ g2,
                                             const float* __restrict__ bb2,
                                             float* __restrict__ out) {
  int row = blockIdx.x * 4 + (threadIdx.x >> 6);
  int l = threadIdx.x & 63;
  size_t base = (size_t)row * H_ + l * 8;
  f32x4 x0 = *(const f32x4*)(ff + base);
  f32x4 x1 = *(const f32x4*)(ff + base + 4);
  float s = x0[0] + x0[1] + x0[2] + x0[3] + x1[0] + x1[1] + x1[2] + x1[3];
  float q = x0[0]*x0[0] + x0[1]*x0[1] + x0[2]*x0[2] + x0[3]*x0[3]
          + x1[0]*x1[0] + x1[1]*x1[1] + x1[2]*x1[2] + x1[3]*x1[3];
#pragma unroll
  for (int m = 1; m < 64; m <<= 1) { s += __shfl_xor(s, m); q += __shfl_xor(q, m); }
  float mean = s * (1.f / 512.f);
  float var = q * (1.f / 512.f) - mean * mean;
  float rstd = rsqrtf(var + 1e-6f);
  f32x4 g0 = *(const f32x4*)(g2 + l * 8), g1v = *(const f32x4*)(g2 + l * 8 + 4);
  f32x4 b0 = *(const f32x4*)(bb2 + l * 8), b1v = *(const f32x4*)(bb2 + l * 8 + 4);
  short8 nv = *(const short8*)(nattn + base);
  f32x4 t0 = *(const f32x4*)(text1 + base), t1 = *(const f32x4*)(text1 + base + 4);
  f32x4 o0, o1;
#pragma unroll
  for (int i = 0; i < 4; ++i) {
    o0[i] = (x0[i] - mean) * rstd * g0[i] + b0[i] + bf2f((unsigned short)nv[i]) + t0[i];
    o1[i] = (x1[i] - mean) * rstd * g1v[i] + b1v[i] + bf2f((unsigned short)nv[4 + i]) + t1[i];
  }
  *(f32x4*)(out + base) = o0;
  *(f32x4*)(out + base + 4) = o1;
}

extern "C" void kernel_launch(void* const* d_in, const int* in_sizes, int n_in,
                              void* d_out, int out_size, void* d_ws, size_t ws_size,
                              hipStream_t stream) {
  const float* text1 = (const float*)d_in[0];
  const float* text2 = (const float*)d_in[1];
  // d_in[2] = text1_mask (unused by reference output)
  const int* mask2 = (const int*)d_in[3];
  const float* W1 = (const float*)d_in[4];
  const float* b1 = (const float*)d_in[5];
  const float* W2 = (const float*)d_in[6];
  const float* b2 = (const float*)d_in[7];
  const float* g1 = (const float*)d_in[8];
  const float* bb1 = (const float*)d_in[9];
  const float* g2 = (const float*)d_in[10];
  const float* bb2 = (const float*)d_in[11];

  const size_t MiB = 1024ull * 1024ull;
  char* ws = (char*)d_ws;
  unsigned short* W1T   = (unsigned short*)(ws + 0 * MiB);          // 1 MiB
  unsigned short* W2T   = (unsigned short*)(ws + 1 * MiB);          // 1 MiB
  float*          lbuf  = (float*)(ws + 2 * MiB);                   // 128 KiB
  float*          rq    = (float*)(ws + 2 * MiB + 256 * 1024);      // 128 KiB
  float*          rk    = (float*)(ws + 2 * MiB + 512 * 1024);      // 128 KiB
  unsigned short* qn    = (unsigned short*)(ws + 4 * MiB);    // 32 MiB [4,36)
  unsigned short* kn    = (unsigned short*)(ws + 36 * MiB);   // 32 MiB [36,68)
  unsigned short* vt    = (unsigned short*)(ws + 68 * MiB);   // 32 MiB [68,100)
  unsigned short* P     = (unsigned short*)(ws + 100 * MiB);  // 64 MiB [100,164) (8-batch chunk)
  unsigned short* O     = (unsigned short*)(ws + 164 * MiB);  // 32 MiB [164,196)
  // aliases (phase-ordered lifetimes; every span checked against concurrent readers):
  unsigned short* nattn = (unsigned short*)(ws + 100 * MiB);  // [100,132) over P-lower: P dead after
                                                              //   pass2; nattn live LN1 -> LN2 (!)
  unsigned short* hbuf  = (unsigned short*)(ws + 132 * MiB);  // [132,196) over P-upper + O:
                                                              //   P dead after pass2, O dead after LN1
  float*          ff    = (float*)(ws + 4 * MiB);             // [4,68) over qn+kn: both dead after
                                                              //   pass1. MUST NOT overlap nattn
                                                              //   [100,132) -- LN2 reads nattn AFTER
                                                              //   FF2 writes ff (round-4 NaN bug).
  float* outp = (float*)d_out;

  hipMemsetAsync(lbuf, 0, (size_t)B_ * S1_ * sizeof(float), stream);

  k_cast<<<dim3(B_ * S1_ / 4), 256, 0, stream>>>(text1, qn, rq);
  k_cast<<<dim3(B_ * S2_ / 4), 256, 0, stream>>>(text2, kn, rk);
  k_tw<<<dim3(512 * 1024 / 256), 256, 0, stream>>>(W1, W1T, 9, 1024);
  k_tw<<<dim3(512 * 1024 / 256), 256, 0, stream>>>(W2, W2T, 10, 512);
  k_tvt<<<dim3(H_ / 64, S2_ / 64, B_), 256, 0, stream>>>(kn, vt);

  for (int c = 0; c < 2; ++c) {
    const int c0 = c * 8;
    // pass1: P = exp((qn @ kn^T)*rq*rk - 1) * mask, row sums -> lbuf
    k_gemm<2><<<dim3(S2_ / 128, S1_ / 128, 8), 256, 0, stream>>>(
        qn + (size_t)c0 * S1_ * H_, kn + (size_t)c0 * S2_ * H_,
        nullptr, mask2 + (size_t)c0 * S2_, rq + (size_t)c0 * S1_, rk + (size_t)c0 * S2_,
        lbuf + (size_t)c0 * S1_, P,
        S1_, S2_, H_, (long)S1_ * H_, (long)S2_ * H_, (long)S1_ * S2_);
    // pass2: O = (P @ V) / l   (bf16)
    k_gemm<3><<<dim3(H_ / 128, S1_ / 128, 8), 256, 0, stream>>>(
        P, vt + (size_t)c0 * H_ * S2_,
        nullptr, nullptr, nullptr, nullptr,
        lbuf + (size_t)c0 * S1_, O + (size_t)c0 * S1_ * H_,
        S1_, H_, S2_, (long)S1_ * S2_, (long)H_ * S2_, (long)S1_ * H_);
  }

  k_ln1<<<dim3(B_ * S1_ / 4), 256, 0, stream>>>(O, g1, bb1, nattn);
  k_gemm<0><<<dim3(1024 / 128, 32768 / 128, 1), 256, 0, stream>>>(
      nattn, W1T, b1, nullptr, nullptr, nullptr, nullptr, hbuf, 32768, 1024, 512, 0, 0, 0);
  k_gemm<1><<<dim3(512 / 128, 32768 / 128, 1), 256, 0, stream>>>(
      hbuf, W2T, b2, nullptr, nullptr, nullptr, nullptr, ff, 32768, 512, 1024, 0, 0, 0);
  k_ln2<<<dim3(32768 / 4), 256, 0, stream>>>(ff, nattn, text1, g2, bb2, outp);
}

// Round 6
// 402.949 us; speedup vs baseline: 1.2869x; 1.0987x over previous
//
#include <hip/hip_runtime.h>
#include <stdint.h>

#define B_ 16
#define S1_ 2048
#define S2_ 2048
#define H_ 512

typedef short short8 __attribute__((ext_vector_type(8)));
typedef float f32x4 __attribute__((ext_vector_type(4)));

__device__ __forceinline__ unsigned short f2bf(float f) {
  unsigned u = __builtin_bit_cast(unsigned, f);
  u += 0x7fffu + ((u >> 16) & 1u);          // round-to-nearest-even
  return (unsigned short)(u >> 16);
}
__device__ __forceinline__ float bf2f(unsigned short us) {
  return __builtin_bit_cast(float, (unsigned)us << 16);
}

__device__ __forceinline__ void gload_lds16(const void* g, void* l) {
  __builtin_amdgcn_global_load_lds((const __attribute__((address_space(1))) void*)g,
                                   (__attribute__((address_space(3))) void*)l,
                                   16, 0, 0);
}

// ---------------- prep: bf16 cast + reciprocal row-norm ----------------
__global__ __launch_bounds__(256) void k_cast(const float* __restrict__ x,
                                              unsigned short* __restrict__ y,
                                              float* __restrict__ rn) {
  int row = blockIdx.x * 4 + (threadIdx.x >> 6);
  int l = threadIdx.x & 63;
  const f32x4* xr = (const f32x4*)(x + (size_t)row * H_) + l * 2;
  f32x4 a = xr[0], b = xr[1];
  float s = a[0]*a[0] + a[1]*a[1] + a[2]*a[2] + a[3]*a[3]
          + b[0]*b[0] + b[1]*b[1] + b[2]*b[2] + b[3]*b[3];
#pragma unroll
  for (int m = 1; m < 64; m <<= 1) s += __shfl_xor(s, m);
  if (l == 0) rn[row] = 1.0f / fmaxf(sqrtf(s), 1e-12f);
  short8 o;
#pragma unroll
  for (int i = 0; i < 4; ++i) { o[i] = (short)f2bf(a[i]); o[4 + i] = (short)f2bf(b[i]); }
  *(short8*)(y + (size_t)row * H_ + l * 8) = o;
}

// ---------------- prep: transpose+cast weights W[R][C] -> WT[C][R] bf16 ----------------
__global__ __launch_bounds__(256) void k_tw(const float* __restrict__ Wm,
                                            unsigned short* __restrict__ WT,
                                            int lgR, int C) {
  int i = blockIdx.x * 256 + threadIdx.x;     // over C*R outputs
  int R = 1 << lgR;
  int n = i >> lgR, k = i & (R - 1);
  WT[i] = f2bf(Wm[(size_t)k * C + n]);
}

// ---------------- prep: vt[b][h][s] = transpose(kn[b][s][h]) (bf16 -> bf16) ----------------
__global__ __launch_bounds__(256) void k_tvt(const unsigned short* __restrict__ kn,
                                             unsigned short* __restrict__ vt) {
  __shared__ unsigned short tile[64][72];
  int h0 = blockIdx.x * 64, s0 = blockIdx.y * 64, b = blockIdx.z;
  int t = threadIdx.x;
#pragma unroll
  for (int p = 0; p < 2; ++p) {
    int si = p * 32 + (t >> 3);
    int cj = (t & 7) * 8;
    short8 v = *(const short8*)(kn + ((size_t)(b * S2_ + s0 + si)) * H_ + h0 + cj);
#pragma unroll
    for (int x = 0; x < 8; ++x) tile[si][cj + x] = (unsigned short)v[x];
  }
  __syncthreads();
#pragma unroll
  for (int p = 0; p < 2; ++p) {
    int ho = p * 32 + (t >> 3);
    int sx = (t & 7) * 8;
    short8 o;
#pragma unroll
    for (int x = 0; x < 8; ++x) o[x] = (short)tile[sx + x][ho];
    *(short8*)(vt + ((size_t)(b * H_ + h0 + ho)) * S2_ + s0 + sx) = o;
  }
}

// ---------------- bf16 MFMA GEMM: 128x128 tile, BK=64, 4 waves, single-buf LDS ----
// Round-2 proven structure: stage -> vmcnt(0) -> barrier -> compute -> barrier.
// 32 KiB LDS keeps 3-4 blocks/CU resident; cross-block TLP hides staging latency
// (measured: dbuf/256-tile variants that cut residency regressed 57 -> 76-78 us).
// MODE 0: FF1 relu(acc+bias) bf16 | MODE 1: FF2 acc+bias f32
// MODE 2: P=exp(acc*rq[m]*rk[n]-1)*mask bf16 + rowsum atomics | MODE 3: acc/lbuf[row] bf16
template <int MODE>
__global__ __launch_bounds__(256, 2) void k_gemm(
    const unsigned short* __restrict__ A, const unsigned short* __restrict__ BT,
    const float* __restrict__ bias, const int* __restrict__ mask,
    const float* __restrict__ rq, const float* __restrict__ rk,
    float* __restrict__ lbuf, void* __restrict__ out,
    int M, int N, int K, long sA, long sB, long sOut) {
  __shared__ unsigned short lA[128 * 64];
  __shared__ unsigned short lB[128 * 64];
  const int z = blockIdx.z;
  const unsigned short* Ab = A + (size_t)z * sA;
  const unsigned short* BTb = BT + (size_t)z * sB;
  const int w = threadIdx.x >> 6, l = threadIdx.x & 63;
  const int lr = l & 15, lk = l >> 4;
  const int m0 = blockIdx.y * 128, n0 = blockIdx.x * 128;
  const int wm = (w >> 1) * 64, wn = (w & 1) * 64;

  // staging: chunk c=j*4+w covers rows 8c..8c+7; lane l covers row 8c+(l>>3),
  // 16 source bytes at col ((l&7)*16) ^ XOR-swizzle; LDS dest linear.
  const int srow = l >> 3;
  const int lswz = ((l & 7) * 16) ^ ((srow & 7) << 4);
  const char* pA = (const char*)Ab + ((size_t)(m0 + w * 8 + srow) * K) * 2 + lswz;
  const char* pB = (const char*)BTb + ((size_t)(n0 + w * 8 + srow) * K) * 2 + lswz;
  const size_t rstep = (size_t)K * 64;   // 32 rows * K * 2B

  f32x4 acc[4][4];
#pragma unroll
  for (int i = 0; i < 4; ++i)
#pragma unroll
    for (int j = 0; j < 4; ++j) acc[i][j] = (f32x4){0.f, 0.f, 0.f, 0.f};

  const int NT = K >> 6;

#pragma unroll 1
  for (int t = 0; t < NT; ++t) {
    const size_t kb = (size_t)t * 128;
#pragma unroll
    for (int j = 0; j < 4; ++j) {
      gload_lds16(pA + j * rstep + kb, (char*)lA + (j * 4 + w) * 1024);
      gload_lds16(pB + j * rstep + kb, (char*)lB + (j * 4 + w) * 1024);
    }
    asm volatile("s_waitcnt vmcnt(0)" ::: "memory");
    __syncthreads();
#pragma unroll
    for (int s = 0; s < 2; ++s) {
      short8 af[4], bf[4];
#pragma unroll
      for (int mi = 0; mi < 4; ++mi) {
        int row = wm + mi * 16 + lr;
        af[mi] = *(const short8*)(lA + row * 64 + ((s * 32 + lk * 8) ^ ((row & 7) << 3)));
      }
#pragma unroll
      for (int ni = 0; ni < 4; ++ni) {
        int row = wn + ni * 16 + lr;
        bf[ni] = *(const short8*)(lB + row * 64 + ((s * 32 + lk * 8) ^ ((row & 7) << 3)));
      }
#pragma unroll
      for (int mi = 0; mi < 4; ++mi)
#pragma unroll
        for (int ni = 0; ni < 4; ++ni)
          acc[mi][ni] = __builtin_amdgcn_mfma_f32_16x16x32_bf16(af[mi], bf[ni], acc[mi][ni], 0, 0, 0);
    }
    __syncthreads();
  }

  if (MODE == 2) {
    float rqv[4][4], rkv[4], mv[4];
#pragma unroll
    for (int mi = 0; mi < 4; ++mi)
#pragma unroll
      for (int r = 0; r < 4; ++r)
        rqv[mi][r] = rq[(size_t)z * M + m0 + wm + mi * 16 + lk * 4 + r];
#pragma unroll
    for (int ni = 0; ni < 4; ++ni) {
      int gn = n0 + wn + ni * 16 + lr;
      rkv[ni] = rk[(size_t)z * N + gn];
      mv[ni] = (mask[(size_t)z * N + gn] != 0) ? 1.0f : 0.0f;
    }
    float rs[4][4];
#pragma unroll
    for (int mi = 0; mi < 4; ++mi)
#pragma unroll
      for (int r = 0; r < 4; ++r) rs[mi][r] = 0.f;
#pragma unroll
    for (int mi = 0; mi < 4; ++mi)
#pragma unroll
      for (int ni = 0; ni < 4; ++ni) {
        int gn = n0 + wn + ni * 16 + lr;
#pragma unroll
        for (int r = 0; r < 4; ++r) {
          int gm = m0 + wm + mi * 16 + lk * 4 + r;
          float p = __expf(acc[mi][ni][r] * rqv[mi][r] * rkv[ni] - 1.0f) * mv[ni];
          rs[mi][r] += p;
          ((unsigned short*)out)[(size_t)z * sOut + (size_t)gm * N + gn] = f2bf(p);
        }
      }
#pragma unroll
    for (int mi = 0; mi < 4; ++mi)
#pragma unroll
      for (int r = 0; r < 4; ++r) {
        float s = rs[mi][r];
        s += __shfl_xor(s, 1); s += __shfl_xor(s, 2); s += __shfl_xor(s, 4); s += __shfl_xor(s, 8);
        if (lr == 0) {
          int gm = m0 + wm + mi * 16 + lk * 4 + r;
          atomicAdd(&lbuf[(size_t)z * M + gm], s);
        }
      }
  } else if (MODE == 3) {
#pragma unroll
    for (int mi = 0; mi < 4; ++mi)
#pragma unroll
      for (int r = 0; r < 4; ++r) {
        int gm = m0 + wm + mi * 16 + lk * 4 + r;
        float rl = 1.0f / lbuf[(size_t)z * M + gm];
#pragma unroll
        for (int ni = 0; ni < 4; ++ni) {
          int gn = n0 + wn + ni * 16 + lr;
          ((unsigned short*)out)[(size_t)z * sOut + (size_t)gm * N + gn] = f2bf(acc[mi][ni][r] * rl);
        }
      }
  } else {
#pragma unroll
    for (int mi = 0; mi < 4; ++mi)
#pragma unroll
      for (int ni = 0; ni < 4; ++ni) {
        int gn = n0 + wn + ni * 16 + lr;
        float bs = bias[gn];
#pragma unroll
        for (int r = 0; r < 4; ++r) {
          int gm = m0 + wm + mi * 16 + lk * 4 + r;
          float v = acc[mi][ni][r] + bs;
          if (MODE == 0) v = fmaxf(v, 0.f);
          if (MODE == 0) ((unsigned short*)out)[(size_t)gm * N + gn] = f2bf(v);
          else           ((float*)out)[(size_t)gm * N + gn] = v;
        }
      }
  }
}

// ---------------- LN1: nattn = LN(O)*g+b (bf16) ----------------
__global__ __launch_bounds__(256) void k_ln1(const unsigned short* __restrict__ O,
                                             const float* __restrict__ g,
                                             const float* __restrict__ bvec,
                                             unsigned short* __restrict__ nattn) {
  int row = blockIdx.x * 4 + (threadIdx.x >> 6);
  int l = threadIdx.x & 63;
  size_t base = (size_t)row * H_ + l * 8;
  short8 ov = *(const short8*)(O + base);
  float x[8];
#pragma unroll
  for (int i = 0; i < 8; ++i) x[i] = bf2f((unsigned short)ov[i]);
  float s = 0.f, q = 0.f;
#pragma unroll
  for (int i = 0; i < 8; ++i) { s += x[i]; q += x[i] * x[i]; }
#pragma unroll
  for (int m = 1; m < 64; m <<= 1) { s += __shfl_xor(s, m); q += __shfl_xor(q, m); }
  float mean = s * (1.f / 512.f);
  float var = q * (1.f / 512.f) - mean * mean;
  float rstd = rsqrtf(var + 1e-6f);
  f32x4 g0 = *(const f32x4*)(g + l * 8), g1v = *(const f32x4*)(g + l * 8 + 4);
  f32x4 b0 = *(const f32x4*)(bvec + l * 8), b1v = *(const f32x4*)(bvec + l * 8 + 4);
  short8 no;
#pragma unroll
  for (int i = 0; i < 4; ++i) {
    no[i]     = (short)f2bf((x[i] - mean) * rstd * g0[i] + b0[i]);
    no[4 + i] = (short)f2bf((x[4 + i] - mean) * rstd * g1v[i] + b1v[i]);
  }
  *(short8*)(nattn + base) = no;
}

// ---------------- LN2(ff) + nattn + text1 -> out ----------------
__global__ __launch_bounds__(256) void k_ln2(const float* __restrict__ ff,
                                             const unsigned short* __restrict__ nattn,
                                             const float* __restrict__ text1,
                                             const float* __restrict__ g2,
                                             const float* __restrict__ bb2,
                                             float* __restrict__ out) {
  int row = blockIdx.x * 4 + (threadIdx.x >> 6);
  int l = threadIdx.x & 63;
  size_t base = (size_t)row * H_ + l * 8;
  f32x4 x0 = *(const f32x4*)(ff + base);
  f32x4 x1 = *(const f32x4*)(ff + base + 4);
  float s = x0[0] + x0[1] + x0[2] + x0[3] + x1[0] + x1[1] + x1[2] + x1[3];
  float q = x0[0]*x0[0] + x0[1]*x0[1] + x0[2]*x0[2] + x0[3]*x0[3]
          + x1[0]*x1[0] + x1[1]*x1[1] + x1[2]*x1[2] + x1[3]*x1[3];
#pragma unroll
  for (int m = 1; m < 64; m <<= 1) { s += __shfl_xor(s, m); q += __shfl_xor(q, m); }
  float mean = s * (1.f / 512.f);
  float var = q * (1.f / 512.f) - mean * mean;
  float rstd = rsqrtf(var + 1e-6f);
  f32x4 g0 = *(const f32x4*)(g2 + l * 8), g1v = *(const f32x4*)(g2 + l * 8 + 4);
  f32x4 b0 = *(const f32x4*)(bb2 + l * 8), b1v = *(const f32x4*)(bb2 + l * 8 + 4);
  short8 nv = *(const short8*)(nattn + base);
  f32x4 t0 = *(const f32x4*)(text1 + base), t1 = *(const f32x4*)(text1 + base + 4);
  f32x4 o0, o1;
#pragma unroll
  for (int i = 0; i < 4; ++i) {
    o0[i] = (x0[i] - mean) * rstd * g0[i] + b0[i] + bf2f((unsigned short)nv[i]) + t0[i];
    o1[i] = (x1[i] - mean) * rstd * g1v[i] + b1v[i] + bf2f((unsigned short)nv[4 + i]) + t1[i];
  }
  *(f32x4*)(out + base) = o0;
  *(f32x4*)(out + base + 4) = o1;
}

extern "C" void kernel_launch(void* const* d_in, const int* in_sizes, int n_in,
                              void* d_out, int out_size, void* d_ws, size_t ws_size,
                              hipStream_t stream) {
  const float* text1 = (const float*)d_in[0];
  const float* text2 = (const float*)d_in[1];
  // d_in[2] = text1_mask (unused by reference output)
  const int* mask2 = (const int*)d_in[3];
  const float* W1 = (const float*)d_in[4];
  const float* b1 = (const float*)d_in[5];
  const float* W2 = (const float*)d_in[6];
  const float* b2 = (const float*)d_in[7];
  const float* g1 = (const float*)d_in[8];
  const float* bb1 = (const float*)d_in[9];
  const float* g2 = (const float*)d_in[10];
  const float* bb2 = (const float*)d_in[11];

  const size_t MiB = 1024ull * 1024ull;
  char* ws = (char*)d_ws;
  unsigned short* W1T   = (unsigned short*)(ws + 0 * MiB);          // 1 MiB
  unsigned short* W2T   = (unsigned short*)(ws + 1 * MiB);          // 1 MiB
  float*          lbuf  = (float*)(ws + 2 * MiB);                   // 128 KiB
  float*          rq    = (float*)(ws + 2 * MiB + 256 * 1024);      // 128 KiB
  float*          rk    = (float*)(ws + 2 * MiB + 512 * 1024);      // 128 KiB
  unsigned short* qn    = (unsigned short*)(ws + 4 * MiB);    // 32 MiB [4,36)
  unsigned short* kn    = (unsigned short*)(ws + 36 * MiB);   // 32 MiB [36,68)
  unsigned short* vt    = (unsigned short*)(ws + 68 * MiB);   // 32 MiB [68,100)
  unsigned short* P     = (unsigned short*)(ws + 100 * MiB);  // 64 MiB [100,164) (8-batch chunk)
  unsigned short* O     = (unsigned short*)(ws + 164 * MiB);  // 32 MiB [164,196)
  // aliases (phase-ordered lifetimes; every span checked against concurrent readers):
  unsigned short* nattn = (unsigned short*)(ws + 100 * MiB);  // [100,132) over P-lower: P dead after
                                                              //   pass2; nattn live LN1 -> LN2 (!)
  unsigned short* hbuf  = (unsigned short*)(ws + 132 * MiB);  // [132,196) over P-upper + O:
                                                              //   P dead after pass2, O dead after LN1
  float*          ff    = (float*)(ws + 4 * MiB);             // [4,68) over qn+kn: both dead after
                                                              //   pass1. MUST NOT overlap nattn
                                                              //   [100,132) -- LN2 reads nattn AFTER
                                                              //   FF2 writes ff (round-4 NaN bug).
  float* outp = (float*)d_out;

  hipMemsetAsync(lbuf, 0, (size_t)B_ * S1_ * sizeof(float), stream);

  k_cast<<<dim3(B_ * S1_ / 4), 256, 0, stream>>>(text1, qn, rq);
  k_cast<<<dim3(B_ * S2_ / 4), 256, 0, stream>>>(text2, kn, rk);
  k_tw<<<dim3(512 * 1024 / 256), 256, 0, stream>>>(W1, W1T, 9, 1024);
  k_tw<<<dim3(512 * 1024 / 256), 256, 0, stream>>>(W2, W2T, 10, 512);
  k_tvt<<<dim3(H_ / 64, S2_ / 64, B_), 256, 0, stream>>>(kn, vt);

  for (int c = 0; c < 2; ++c) {
    const int c0 = c * 8;
    // pass1: P = exp((qn @ kn^T)*rq*rk - 1) * mask, row sums -> lbuf
    k_gemm<2><<<dim3(S2_ / 128, S1_ / 128, 8), 256, 0, stream>>>(
        qn + (size_t)c0 * S1_ * H_, kn + (size_t)c0 * S2_ * H_,
        nullptr, mask2 + (size_t)c0 * S2_, rq + (size_t)c0 * S1_, rk + (size_t)c0 * S2_,
        lbuf + (size_t)c0 * S1_, P,
        S1_, S2_, H_, (long)S1_ * H_, (long)S2_ * H_, (long)S1_ * S2_);
    // pass2: O = (P @ V) / l   (bf16)
    k_gemm<3><<<dim3(H_ / 128, S1_ / 128, 8), 256, 0, stream>>>(
        P, vt + (size_t)c0 * H_ * S2_,
        nullptr, nullptr, nullptr, nullptr,
        lbuf + (size_t)c0 * S1_, O + (size_t)c0 * S1_ * H_,
        S1_, H_, S2_, (long)S1_ * S2_, (long)H_ * S2_, (long)S1_ * H_);
  }

  k_ln1<<<dim3(B_ * S1_ / 4), 256, 0, stream>>>(O, g1, bb1, nattn);
  k_gemm<0><<<dim3(1024 / 128, 32768 / 128, 1), 256, 0, stream>>>(
      nattn, W1T, b1, nullptr, nullptr, nullptr, nullptr, hbuf, 32768, 1024, 512, 0, 0, 0);
  k_gemm<1><<<dim3(512 / 128, 32768 / 128, 1), 256, 0, stream>>>(
      hbuf, W2T, b2, nullptr, nullptr, nullptr, nullptr, ff, 32768, 512, 1024, 0, 0, 0);
  k_ln2<<<dim3(32768 / 4), 256, 0, stream>>>(ff, nattn, text1, g2, bb2, outp);
}

// Round 7
// 366.087 us; speedup vs baseline: 1.4165x; 1.1007x over previous
//
#include <hip/hip_runtime.h>
#include <stdint.h>

#define B_ 16
#define S1_ 2048
#define S2_ 2048
#define H_ 512

typedef short short8 __attribute__((ext_vector_type(8)));
typedef float f32x4 __attribute__((ext_vector_type(4)));

__device__ __forceinline__ unsigned short f2bf(float f) {
  unsigned u = __builtin_bit_cast(unsigned, f);
  u += 0x7fffu + ((u >> 16) & 1u);          // round-to-nearest-even
  return (unsigned short)(u >> 16);
}
__device__ __forceinline__ float bf2f(unsigned short us) {
  return __builtin_bit_cast(float, (unsigned)us << 16);
}

__device__ __forceinline__ void gload_lds16(const void* g, void* l) {
  __builtin_amdgcn_global_load_lds((const __attribute__((address_space(1))) void*)g,
                                   (__attribute__((address_space(3))) void*)l,
                                   16, 0, 0);
}

// ---------------- prep: bf16 cast + reciprocal row-norm ----------------
__global__ __launch_bounds__(256) void k_cast(const float* __restrict__ x,
                                              unsigned short* __restrict__ y,
                                              float* __restrict__ rn) {
  int row = blockIdx.x * 4 + (threadIdx.x >> 6);
  int l = threadIdx.x & 63;
  const f32x4* xr = (const f32x4*)(x + (size_t)row * H_) + l * 2;
  f32x4 a = xr[0], b = xr[1];
  float s = a[0]*a[0] + a[1]*a[1] + a[2]*a[2] + a[3]*a[3]
          + b[0]*b[0] + b[1]*b[1] + b[2]*b[2] + b[3]*b[3];
#pragma unroll
  for (int m = 1; m < 64; m <<= 1) s += __shfl_xor(s, m);
  if (l == 0) rn[row] = 1.0f / fmaxf(sqrtf(s), 1e-12f);
  short8 o;
#pragma unroll
  for (int i = 0; i < 4; ++i) { o[i] = (short)f2bf(a[i]); o[4 + i] = (short)f2bf(b[i]); }
  *(short8*)(y + (size_t)row * H_ + l * 8) = o;
}

// ---------------- prep: transpose+cast weights W[R][C] -> WT[C][R] bf16 ----------------
__global__ __launch_bounds__(256) void k_tw(const float* __restrict__ Wm,
                                            unsigned short* __restrict__ WT,
                                            int lgR, int C) {
  int i = blockIdx.x * 256 + threadIdx.x;     // over C*R outputs
  int R = 1 << lgR;
  int n = i >> lgR, k = i & (R - 1);
  WT[i] = f2bf(Wm[(size_t)k * C + n]);
}

// ---------------- prep: vt[b][h][s] = transpose(kn[b][s][h]) (bf16 -> bf16) ----------------
__global__ __launch_bounds__(256) void k_tvt(const unsigned short* __restrict__ kn,
                                             unsigned short* __restrict__ vt) {
  __shared__ unsigned short tile[64][72];
  int h0 = blockIdx.x * 64, s0 = blockIdx.y * 64, b = blockIdx.z;
  int t = threadIdx.x;
#pragma unroll
  for (int p = 0; p < 2; ++p) {
    int si = p * 32 + (t >> 3);
    int cj = (t & 7) * 8;
    short8 v = *(const short8*)(kn + ((size_t)(b * S2_ + s0 + si)) * H_ + h0 + cj);
#pragma unroll
    for (int x = 0; x < 8; ++x) tile[si][cj + x] = (unsigned short)v[x];
  }
  __syncthreads();
#pragma unroll
  for (int p = 0; p < 2; ++p) {
    int ho = p * 32 + (t >> 3);
    int sx = (t & 7) * 8;
    short8 o;
#pragma unroll
    for (int x = 0; x < 8; ++x) o[x] = (short)tile[sx + x][ho];
    *(short8*)(vt + ((size_t)(b * H_ + h0 + ho)) * S2_ + s0 + sx) = o;
  }
}

// ---------------- bf16 MFMA GEMM: 128x128 tile, BK=64, 4 waves, single-buf LDS ----
// Round-2 proven structure: stage -> vmcnt(0) -> barrier -> compute -> barrier.
// 32 KiB LDS keeps blocks/CU residency high; cross-block TLP hides staging latency
// (measured: dbuf/256-tile variants that cut residency regressed 57 -> 76-78 us).
// XCD-aware bijective block swizzle (T1): consecutive logical tiles (sharing an
// A-panel) land on the SAME XCD's L2. Requires nwg % 8 == 0 (all our grids).
// MODE 0: FF1 relu(acc+bias) bf16 | MODE 1: FF2 acc+bias bf16
// MODE 2: P=exp(acc*rq[m]*rk[n]-1)*mask bf16 + rowsum atomics | MODE 3: acc/lbuf[row] bf16
template <int MODE>
__global__ __launch_bounds__(256, 2) void k_gemm(
    const unsigned short* __restrict__ A, const unsigned short* __restrict__ BT,
    const float* __restrict__ bias, const int* __restrict__ mask,
    const float* __restrict__ rq, const float* __restrict__ rk,
    float* __restrict__ lbuf, void* __restrict__ out,
    int M, int N, int K, long sA, long sB, long sOut) {
  __shared__ unsigned short lA[128 * 64];
  __shared__ unsigned short lB[128 * 64];

  // ---- XCD swizzle: logical (bx,by,z) from hw block id ----
  const int gx = gridDim.x, gy = gridDim.y;
  const int nwg = gx * gy * (int)gridDim.z;
  int orig = ((int)blockIdx.z * gy + (int)blockIdx.y) * gx + (int)blockIdx.x;
  int swzid = ((nwg & 7) == 0) ? ((orig & 7) * (nwg >> 3) + (orig >> 3)) : orig;
  const int z = swzid / (gx * gy);
  int rem = swzid - z * (gx * gy);
  const int by = rem / gx;
  const int bx = rem - by * gx;

  const unsigned short* Ab = A + (size_t)z * sA;
  const unsigned short* BTb = BT + (size_t)z * sB;
  const int w = threadIdx.x >> 6, l = threadIdx.x & 63;
  const int lr = l & 15, lk = l >> 4;
  const int m0 = by * 128, n0 = bx * 128;
  const int wm = (w >> 1) * 64, wn = (w & 1) * 64;

  // staging: chunk c=j*4+w covers rows 8c..8c+7; lane l covers row 8c+(l>>3),
  // 16 source bytes at col ((l&7)*16) ^ XOR-swizzle; LDS dest linear.
  const int srow = l >> 3;
  const int lswz = ((l & 7) * 16) ^ ((srow & 7) << 4);
  const char* pA = (const char*)Ab + ((size_t)(m0 + w * 8 + srow) * K) * 2 + lswz;
  const char* pB = (const char*)BTb + ((size_t)(n0 + w * 8 + srow) * K) * 2 + lswz;
  const size_t rstep = (size_t)K * 64;   // 32 rows * K * 2B

  f32x4 acc[4][4];
#pragma unroll
  for (int i = 0; i < 4; ++i)
#pragma unroll
    for (int j = 0; j < 4; ++j) acc[i][j] = (f32x4){0.f, 0.f, 0.f, 0.f};

  const int NT = K >> 6;

#pragma unroll 1
  for (int t = 0; t < NT; ++t) {
    const size_t kb = (size_t)t * 128;
#pragma unroll
    for (int j = 0; j < 4; ++j) {
      gload_lds16(pA + j * rstep + kb, (char*)lA + (j * 4 + w) * 1024);
      gload_lds16(pB + j * rstep + kb, (char*)lB + (j * 4 + w) * 1024);
    }
    asm volatile("s_waitcnt vmcnt(0)" ::: "memory");
    __syncthreads();
#pragma unroll
    for (int s = 0; s < 2; ++s) {
      short8 af[4], bf[4];
#pragma unroll
      for (int mi = 0; mi < 4; ++mi) {
        int row = wm + mi * 16 + lr;
        af[mi] = *(const short8*)(lA + row * 64 + ((s * 32 + lk * 8) ^ ((row & 7) << 3)));
      }
#pragma unroll
      for (int ni = 0; ni < 4; ++ni) {
        int row = wn + ni * 16 + lr;
        bf[ni] = *(const short8*)(lB + row * 64 + ((s * 32 + lk * 8) ^ ((row & 7) << 3)));
      }
#pragma unroll
      for (int mi = 0; mi < 4; ++mi)
#pragma unroll
        for (int ni = 0; ni < 4; ++ni)
          acc[mi][ni] = __builtin_amdgcn_mfma_f32_16x16x32_bf16(af[mi], bf[ni], acc[mi][ni], 0, 0, 0);
    }
    __syncthreads();
  }

  if (MODE == 2) {
    float rqv[4][4], rkv[4], mv[4];
#pragma unroll
    for (int mi = 0; mi < 4; ++mi)
#pragma unroll
      for (int r = 0; r < 4; ++r)
        rqv[mi][r] = rq[(size_t)z * M + m0 + wm + mi * 16 + lk * 4 + r];
#pragma unroll
    for (int ni = 0; ni < 4; ++ni) {
      int gn = n0 + wn + ni * 16 + lr;
      rkv[ni] = rk[(size_t)z * N + gn];
      mv[ni] = (mask[(size_t)z * N + gn] != 0) ? 1.0f : 0.0f;
    }
    float rs[4][4];
#pragma unroll
    for (int mi = 0; mi < 4; ++mi)
#pragma unroll
      for (int r = 0; r < 4; ++r) rs[mi][r] = 0.f;
#pragma unroll
    for (int mi = 0; mi < 4; ++mi)
#pragma unroll
      for (int ni = 0; ni < 4; ++ni) {
        int gn = n0 + wn + ni * 16 + lr;
#pragma unroll
        for (int r = 0; r < 4; ++r) {
          int gm = m0 + wm + mi * 16 + lk * 4 + r;
          float p = __expf(acc[mi][ni][r] * rqv[mi][r] * rkv[ni] - 1.0f) * mv[ni];
          rs[mi][r] += p;
          ((unsigned short*)out)[(size_t)z * sOut + (size_t)gm * N + gn] = f2bf(p);
        }
      }
#pragma unroll
    for (int mi = 0; mi < 4; ++mi)
#pragma unroll
      for (int r = 0; r < 4; ++r) {
        float s = rs[mi][r];
        s += __shfl_xor(s, 1); s += __shfl_xor(s, 2); s += __shfl_xor(s, 4); s += __shfl_xor(s, 8);
        if (lr == 0) {
          int gm = m0 + wm + mi * 16 + lk * 4 + r;
          atomicAdd(&lbuf[(size_t)z * M + gm], s);
        }
      }
  } else if (MODE == 3) {
#pragma unroll
    for (int mi = 0; mi < 4; ++mi)
#pragma unroll
      for (int r = 0; r < 4; ++r) {
        int gm = m0 + wm + mi * 16 + lk * 4 + r;
        float rl = 1.0f / lbuf[(size_t)z * M + gm];
#pragma unroll
        for (int ni = 0; ni < 4; ++ni) {
          int gn = n0 + wn + ni * 16 + lr;
          ((unsigned short*)out)[(size_t)z * sOut + (size_t)gm * N + gn] = f2bf(acc[mi][ni][r] * rl);
        }
      }
  } else {
#pragma unroll
    for (int mi = 0; mi < 4; ++mi)
#pragma unroll
      for (int ni = 0; ni < 4; ++ni) {
        int gn = n0 + wn + ni * 16 + lr;
        float bs = bias[gn];
#pragma unroll
        for (int r = 0; r < 4; ++r) {
          int gm = m0 + wm + mi * 16 + lk * 4 + r;
          float v = acc[mi][ni][r] + bs;
          if (MODE == 0) v = fmaxf(v, 0.f);
          ((unsigned short*)out)[(size_t)gm * N + gn] = f2bf(v);
        }
      }
  }
}

// ---------------- LN1: nattn = LN(O)*g+b (bf16) ----------------
__global__ __launch_bounds__(256) void k_ln1(const unsigned short* __restrict__ O,
                                             const float* __restrict__ g,
                                             const float* __restrict__ bvec,
                                             unsigned short* __restrict__ nattn) {
  int row = blockIdx.x * 4 + (threadIdx.x >> 6);
  int l = threadIdx.x & 63;
  size_t base = (size_t)row * H_ + l * 8;
  short8 ov = *(const short8*)(O + base);
  float x[8];
#pragma unroll
  for (int i = 0; i < 8; ++i) x[i] = bf2f((unsigned short)ov[i]);
  float s = 0.f, q = 0.f;
#pragma unroll
  for (int i = 0; i < 8; ++i) { s += x[i]; q += x[i] * x[i]; }
#pragma unroll
  for (int m = 1; m < 64; m <<= 1) { s += __shfl_xor(s, m); q += __shfl_xor(q, m); }
  float mean = s * (1.f / 512.f);
  float var = q * (1.f / 512.f) - mean * mean;
  float rstd = rsqrtf(var + 1e-6f);
  f32x4 g0 = *(const f32x4*)(g + l * 8), g1v = *(const f32x4*)(g + l * 8 + 4);
  f32x4 b0 = *(const f32x4*)(bvec + l * 8), b1v = *(const f32x4*)(bvec + l * 8 + 4);
  short8 no;
#pragma unroll
  for (int i = 0; i < 4; ++i) {
    no[i]     = (short)f2bf((x[i] - mean) * rstd * g0[i] + b0[i]);
    no[4 + i] = (short)f2bf((x[4 + i] - mean) * rstd * g1v[i] + b1v[i]);
  }
  *(short8*)(nattn + base) = no;
}

// ---------------- LN2(ff bf16) + nattn + text1 -> out ----------------
__global__ __launch_bounds__(256) void k_ln2(const unsigned short* __restrict__ ff,
                                             const unsigned short* __restrict__ nattn,
                                             const float* __restrict__ text1,
                                             const float* __restrict__ g2,
                                             const float* __restrict__ bb2,
                                             float* __restrict__ out) {
  int row = blockIdx.x * 4 + (threadIdx.x >> 6);
  int l = threadIdx.x & 63;
  size_t base = (size_t)row * H_ + l * 8;
  short8 fv = *(const short8*)(ff + base);
  float x[8];
#pragma unroll
  for (int i = 0; i < 8; ++i) x[i] = bf2f((unsigned short)fv[i]);
  float s = 0.f, q = 0.f;
#pragma unroll
  for (int i = 0; i < 8; ++i) { s += x[i]; q += x[i] * x[i]; }
#pragma unroll
  for (int m = 1; m < 64; m <<= 1) { s += __shfl_xor(s, m); q += __shfl_xor(q, m); }
  float mean = s * (1.f / 512.f);
  float var = q * (1.f / 512.f) - mean * mean;
  float rstd = rsqrtf(var + 1e-6f);
  f32x4 g0 = *(const f32x4*)(g2 + l * 8), g1v = *(const f32x4*)(g2 + l * 8 + 4);
  f32x4 b0 = *(const f32x4*)(bb2 + l * 8), b1v = *(const f32x4*)(bb2 + l * 8 + 4);
  short8 nv = *(const short8*)(nattn + base);
  f32x4 t0 = *(const f32x4*)(text1 + base), t1 = *(const f32x4*)(text1 + base + 4);
  f32x4 o0, o1;
#pragma unroll
  for (int i = 0; i < 4; ++i) {
    o0[i] = (x[i] - mean) * rstd * g0[i] + b0[i] + bf2f((unsigned short)nv[i]) + t0[i];
    o1[i] = (x[4 + i] - mean) * rstd * g1v[i] + b1v[i] + bf2f((unsigned short)nv[4 + i]) + t1[i];
  }
  *(f32x4*)(out + base) = o0;
  *(f32x4*)(out + base + 4) = o1;
}

extern "C" void kernel_launch(void* const* d_in, const int* in_sizes, int n_in,
                              void* d_out, int out_size, void* d_ws, size_t ws_size,
                              hipStream_t stream) {
  const float* text1 = (const float*)d_in[0];
  const float* text2 = (const float*)d_in[1];
  // d_in[2] = text1_mask (unused by reference output)
  const int* mask2 = (const int*)d_in[3];
  const float* W1 = (const float*)d_in[4];
  const float* b1 = (const float*)d_in[5];
  const float* W2 = (const float*)d_in[6];
  const float* b2 = (const float*)d_in[7];
  const float* g1 = (const float*)d_in[8];
  const float* bb1 = (const float*)d_in[9];
  const float* g2 = (const float*)d_in[10];
  const float* bb2 = (const float*)d_in[11];

  const size_t MiB = 1024ull * 1024ull;
  char* ws = (char*)d_ws;
  unsigned short* W1T   = (unsigned short*)(ws + 0 * MiB);          // 1 MiB
  unsigned short* W2T   = (unsigned short*)(ws + 1 * MiB);          // 1 MiB
  float*          lbuf  = (float*)(ws + 2 * MiB);                   // 128 KiB
  float*          rq    = (float*)(ws + 2 * MiB + 256 * 1024);      // 128 KiB
  float*          rk    = (float*)(ws + 2 * MiB + 512 * 1024);      // 128 KiB
  unsigned short* qn    = (unsigned short*)(ws + 4 * MiB);    // 32 MiB [4,36)
  unsigned short* kn    = (unsigned short*)(ws + 36 * MiB);   // 32 MiB [36,68)
  unsigned short* vt    = (unsigned short*)(ws + 68 * MiB);   // 32 MiB [68,100)
  unsigned short* P     = (unsigned short*)(ws + 100 * MiB);  // 64 MiB [100,164) (8-batch chunk)
  unsigned short* O     = (unsigned short*)(ws + 164 * MiB);  // 32 MiB [164,196)
  // aliases (phase-ordered lifetimes; every span checked against concurrent readers):
  unsigned short* nattn = (unsigned short*)(ws + 100 * MiB);  // [100,132) over P-lower: P dead after
                                                              //   pass2; nattn live LN1 -> LN2 (!)
  unsigned short* hbuf  = (unsigned short*)(ws + 132 * MiB);  // [132,196) over P-upper + O:
                                                              //   P dead after pass2, O dead after LN1
  unsigned short* ffb   = (unsigned short*)(ws + 4 * MiB);    // [4,36) bf16 over qn: dead after pass1.
                                                              //   MUST NOT overlap nattn [100,132):
                                                              //   LN2 reads nattn AFTER FF2 writes ff
                                                              //   (round-4 NaN bug).
  float* outp = (float*)d_out;

  hipMemsetAsync(lbuf, 0, (size_t)B_ * S1_ * sizeof(float), stream);

  k_cast<<<dim3(B_ * S1_ / 4), 256, 0, stream>>>(text1, qn, rq);
  k_cast<<<dim3(B_ * S2_ / 4), 256, 0, stream>>>(text2, kn, rk);
  k_tw<<<dim3(512 * 1024 / 256), 256, 0, stream>>>(W1, W1T, 9, 1024);
  k_tw<<<dim3(512 * 1024 / 256), 256, 0, stream>>>(W2, W2T, 10, 512);
  k_tvt<<<dim3(H_ / 64, S2_ / 64, B_), 256, 0, stream>>>(kn, vt);

  for (int c = 0; c < 2; ++c) {
    const int c0 = c * 8;
    // pass1: P = exp((qn @ kn^T)*rq*rk - 1) * mask, row sums -> lbuf
    k_gemm<2><<<dim3(S2_ / 128, S1_ / 128, 8), 256, 0, stream>>>(
        qn + (size_t)c0 * S1_ * H_, kn + (size_t)c0 * S2_ * H_,
        nullptr, mask2 + (size_t)c0 * S2_, rq + (size_t)c0 * S1_, rk + (size_t)c0 * S2_,
        lbuf + (size_t)c0 * S1_, P,
        S1_, S2_, H_, (long)S1_ * H_, (long)S2_ * H_, (long)S1_ * S2_);
    // pass2: O = (P @ V) / l   (bf16)
    k_gemm<3><<<dim3(H_ / 128, S1_ / 128, 8), 256, 0, stream>>>(
        P, vt + (size_t)c0 * H_ * S2_,
        nullptr, nullptr, nullptr, nullptr,
        lbuf + (size_t)c0 * S1_, O + (size_t)c0 * S1_ * H_,
        S1_, H_, S2_, (long)S1_ * S2_, (long)H_ * S2_, (long)S1_ * H_);
  }

  k_ln1<<<dim3(B_ * S1_ / 4), 256, 0, stream>>>(O, g1, bb1, nattn);
  k_gemm<0><<<dim3(1024 / 128, 32768 / 128, 1), 256, 0, stream>>>(
      nattn, W1T, b1, nullptr, nullptr, nullptr, nullptr, hbuf, 32768, 1024, 512, 0, 0, 0);
  k_gemm<1><<<dim3(512 / 128, 32768 / 128, 1), 256, 0, stream>>>(
      hbuf, W2T, b2, nullptr, nullptr, nullptr, nullptr, ffb, 32768, 512, 1024, 0, 0, 0);
  k_ln2<<<dim3(32768 / 4), 256, 0, stream>>>(ffb, nattn, text1, g2, bb2, outp);
}

// Round 8
// 350.617 us; speedup vs baseline: 1.4790x; 1.0441x over previous
//
#include <hip/hip_runtime.h>
#include <stdint.h>

#define B_ 16
#define S1_ 2048
#define S2_ 2048
#define H_ 512

typedef short short8 __attribute__((ext_vector_type(8)));
typedef float f32x4 __attribute__((ext_vector_type(4)));

__device__ __forceinline__ unsigned short f2bf(float f) {
  unsigned u = __builtin_bit_cast(unsigned, f);
  u += 0x7fffu + ((u >> 16) & 1u);          // round-to-nearest-even
  return (unsigned short)(u >> 16);
}
__device__ __forceinline__ float bf2f(unsigned short us) {
  return __builtin_bit_cast(float, (unsigned)us << 16);
}

__device__ __forceinline__ void gload_lds16(const void* g, void* l) {
  __builtin_amdgcn_global_load_lds((const __attribute__((address_space(1))) void*)g,
                                   (__attribute__((address_space(3))) void*)l,
                                   16, 0, 0);
}

// ---------------- prep: bf16 cast + reciprocal row-norm ----------------
__global__ __launch_bounds__(256) void k_cast(const float* __restrict__ x,
                                              unsigned short* __restrict__ y,
                                              float* __restrict__ rn) {
  int row = blockIdx.x * 4 + (threadIdx.x >> 6);
  int l = threadIdx.x & 63;
  const f32x4* xr = (const f32x4*)(x + (size_t)row * H_) + l * 2;
  f32x4 a = xr[0], b = xr[1];
  float s = a[0]*a[0] + a[1]*a[1] + a[2]*a[2] + a[3]*a[3]
          + b[0]*b[0] + b[1]*b[1] + b[2]*b[2] + b[3]*b[3];
#pragma unroll
  for (int m = 1; m < 64; m <<= 1) s += __shfl_xor(s, m);
  if (l == 0) rn[row] = 1.0f / fmaxf(sqrtf(s), 1e-12f);
  short8 o;
#pragma unroll
  for (int i = 0; i < 4; ++i) { o[i] = (short)f2bf(a[i]); o[4 + i] = (short)f2bf(b[i]); }
  *(short8*)(y + (size_t)row * H_ + l * 8) = o;
}

// ---------------- prep: transpose+cast weights W[R][C] -> WT[C][R] bf16 ----------------
__global__ __launch_bounds__(256) void k_tw(const float* __restrict__ Wm,
                                            unsigned short* __restrict__ WT,
                                            int lgR, int C) {
  int i = blockIdx.x * 256 + threadIdx.x;     // over C*R outputs
  int R = 1 << lgR;
  int n = i >> lgR, k = i & (R - 1);
  WT[i] = f2bf(Wm[(size_t)k * C + n]);
}

// ---------------- prep: vt[b][h][s] = transpose(kn[b][s][h]) (bf16 -> bf16) ----------------
__global__ __launch_bounds__(256) void k_tvt(const unsigned short* __restrict__ kn,
                                             unsigned short* __restrict__ vt) {
  __shared__ unsigned short tile[64][72];
  int h0 = blockIdx.x * 64, s0 = blockIdx.y * 64, b = blockIdx.z;
  int t = threadIdx.x;
#pragma unroll
  for (int p = 0; p < 2; ++p) {
    int si = p * 32 + (t >> 3);
    int cj = (t & 7) * 8;
    short8 v = *(const short8*)(kn + ((size_t)(b * S2_ + s0 + si)) * H_ + h0 + cj);
#pragma unroll
    for (int x = 0; x < 8; ++x) tile[si][cj + x] = (unsigned short)v[x];
  }
  __syncthreads();
#pragma unroll
  for (int p = 0; p < 2; ++p) {
    int ho = p * 32 + (t >> 3);
    int sx = (t & 7) * 8;
    short8 o;
#pragma unroll
    for (int x = 0; x < 8; ++x) o[x] = (short)tile[sx + x][ho];
    *(short8*)(vt + ((size_t)(b * H_ + h0 + ho)) * S2_ + s0 + sx) = o;
  }
}

// ---------------- bf16 MFMA GEMM: 128x128 tile, BK=64, 4 waves, single-buf LDS ----
// Round-2 proven structure: stage -> vmcnt(0) -> barrier -> compute -> barrier.
// 32 KiB LDS keeps blocks/CU residency high; cross-block TLP hides staging latency.
// SWZ=1: XCD-aware bijective block swizzle (T1) -- groups contiguous logical tiles
// per XCD so shared panels stay in that XCD's L2. Measured: helps pass2/FF (B-panel
// becomes L2-resident per XCD); HURT pass1 (~+7us: same-row atomics concentrated on
// one XCD + per-z working set == L2 size), so pass1 uses SWZ=0.
// MODE 0: FF1 relu(acc+bias) bf16 | MODE 1: FF2 acc+bias bf16
// MODE 2: P=exp(acc*rq[m]*rk[n]-1)*mask bf16 + rowsum atomics | MODE 3: acc/lbuf[row] bf16
template <int MODE, int SWZ>
__global__ __launch_bounds__(256, 2) void k_gemm(
    const unsigned short* __restrict__ A, const unsigned short* __restrict__ BT,
    const float* __restrict__ bias, const int* __restrict__ mask,
    const float* __restrict__ rq, const float* __restrict__ rk,
    float* __restrict__ lbuf, void* __restrict__ out,
    int M, int N, int K, long sA, long sB, long sOut) {
  __shared__ unsigned short lA[128 * 64];
  __shared__ unsigned short lB[128 * 64];

  int bx, by, z;
  if (SWZ) {
    const int gx = gridDim.x, gy = gridDim.y;
    const int nwg = gx * gy * (int)gridDim.z;
    int orig = ((int)blockIdx.z * gy + (int)blockIdx.y) * gx + (int)blockIdx.x;
    int swzid = ((nwg & 7) == 0) ? ((orig & 7) * (nwg >> 3) + (orig >> 3)) : orig;
    z = swzid / (gx * gy);
    int rem = swzid - z * (gx * gy);
    by = rem / gx;
    bx = rem - by * gx;
  } else {
    bx = blockIdx.x; by = blockIdx.y; z = blockIdx.z;
  }

  const unsigned short* Ab = A + (size_t)z * sA;
  const unsigned short* BTb = BT + (size_t)z * sB;
  const int w = threadIdx.x >> 6, l = threadIdx.x & 63;
  const int lr = l & 15, lk = l >> 4;
  const int m0 = by * 128, n0 = bx * 128;
  const int wm = (w >> 1) * 64, wn = (w & 1) * 64;

  // staging: chunk c=j*4+w covers rows 8c..8c+7; lane l covers row 8c+(l>>3),
  // 16 source bytes at col ((l&7)*16) ^ XOR-swizzle; LDS dest linear.
  const int srow = l >> 3;
  const int lswz = ((l & 7) * 16) ^ ((srow & 7) << 4);
  const char* pA = (const char*)Ab + ((size_t)(m0 + w * 8 + srow) * K) * 2 + lswz;
  const char* pB = (const char*)BTb + ((size_t)(n0 + w * 8 + srow) * K) * 2 + lswz;
  const size_t rstep = (size_t)K * 64;   // 32 rows * K * 2B

  f32x4 acc[4][4];
#pragma unroll
  for (int i = 0; i < 4; ++i)
#pragma unroll
    for (int j = 0; j < 4; ++j) acc[i][j] = (f32x4){0.f, 0.f, 0.f, 0.f};

  const int NT = K >> 6;

#pragma unroll 1
  for (int t = 0; t < NT; ++t) {
    const size_t kb = (size_t)t * 128;
#pragma unroll
    for (int j = 0; j < 4; ++j) {
      gload_lds16(pA + j * rstep + kb, (char*)lA + (j * 4 + w) * 1024);
      gload_lds16(pB + j * rstep + kb, (char*)lB + (j * 4 + w) * 1024);
    }
    asm volatile("s_waitcnt vmcnt(0)" ::: "memory");
    __syncthreads();
#pragma unroll
    for (int s = 0; s < 2; ++s) {
      short8 af[4], bf[4];
#pragma unroll
      for (int mi = 0; mi < 4; ++mi) {
        int row = wm + mi * 16 + lr;
        af[mi] = *(const short8*)(lA + row * 64 + ((s * 32 + lk * 8) ^ ((row & 7) << 3)));
      }
#pragma unroll
      for (int ni = 0; ni < 4; ++ni) {
        int row = wn + ni * 16 + lr;
        bf[ni] = *(const short8*)(lB + row * 64 + ((s * 32 + lk * 8) ^ ((row & 7) << 3)));
      }
#pragma unroll
      for (int mi = 0; mi < 4; ++mi)
#pragma unroll
        for (int ni = 0; ni < 4; ++ni)
          acc[mi][ni] = __builtin_amdgcn_mfma_f32_16x16x32_bf16(af[mi], bf[ni], acc[mi][ni], 0, 0, 0);
    }
    __syncthreads();
  }

  if (MODE == 2) {
    float rqv[4][4], rkv[4], mv[4];
#pragma unroll
    for (int mi = 0; mi < 4; ++mi)
#pragma unroll
      for (int r = 0; r < 4; ++r)
        rqv[mi][r] = rq[(size_t)z * M + m0 + wm + mi * 16 + lk * 4 + r];
#pragma unroll
    for (int ni = 0; ni < 4; ++ni) {
      int gn = n0 + wn + ni * 16 + lr;
      rkv[ni] = rk[(size_t)z * N + gn];
      mv[ni] = (mask[(size_t)z * N + gn] != 0) ? 1.0f : 0.0f;
    }
    float rs[4][4];
#pragma unroll
    for (int mi = 0; mi < 4; ++mi)
#pragma unroll
      for (int r = 0; r < 4; ++r) rs[mi][r] = 0.f;
#pragma unroll
    for (int mi = 0; mi < 4; ++mi)
#pragma unroll
      for (int ni = 0; ni < 4; ++ni) {
        int gn = n0 + wn + ni * 16 + lr;
#pragma unroll
        for (int r = 0; r < 4; ++r) {
          int gm = m0 + wm + mi * 16 + lk * 4 + r;
          float p = __expf(acc[mi][ni][r] * rqv[mi][r] * rkv[ni] - 1.0f) * mv[ni];
          rs[mi][r] += p;
          ((unsigned short*)out)[(size_t)z * sOut + (size_t)gm * N + gn] = f2bf(p);
        }
      }
#pragma unroll
    for (int mi = 0; mi < 4; ++mi)
#pragma unroll
      for (int r = 0; r < 4; ++r) {
        float s = rs[mi][r];
        s += __shfl_xor(s, 1); s += __shfl_xor(s, 2); s += __shfl_xor(s, 4); s += __shfl_xor(s, 8);
        if (lr == 0) {
          int gm = m0 + wm + mi * 16 + lk * 4 + r;
          atomicAdd(&lbuf[(size_t)z * M + gm], s);
        }
      }
  } else if (MODE == 3) {
#pragma unroll
    for (int mi = 0; mi < 4; ++mi)
#pragma unroll
      for (int r = 0; r < 4; ++r) {
        int gm = m0 + wm + mi * 16 + lk * 4 + r;
        float rl = 1.0f / lbuf[(size_t)z * M + gm];
#pragma unroll
        for (int ni = 0; ni < 4; ++ni) {
          int gn = n0 + wn + ni * 16 + lr;
          ((unsigned short*)out)[(size_t)z * sOut + (size_t)gm * N + gn] = f2bf(acc[mi][ni][r] * rl);
        }
      }
  } else {
#pragma unroll
    for (int mi = 0; mi < 4; ++mi)
#pragma unroll
      for (int ni = 0; ni < 4; ++ni) {
        int gn = n0 + wn + ni * 16 + lr;
        float bs = bias[gn];
#pragma unroll
        for (int r = 0; r < 4; ++r) {
          int gm = m0 + wm + mi * 16 + lk * 4 + r;
          float v = acc[mi][ni][r] + bs;
          if (MODE == 0) v = fmaxf(v, 0.f);
          ((unsigned short*)out)[(size_t)gm * N + gn] = f2bf(v);
        }
      }
  }
}

// ---------------- LN1: nattn = LN(O)*g+b (bf16) ----------------
__global__ __launch_bounds__(256) void k_ln1(const unsigned short* __restrict__ O,
                                             const float* __restrict__ g,
                                             const float* __restrict__ bvec,
                                             unsigned short* __restrict__ nattn) {
  int row = blockIdx.x * 4 + (threadIdx.x >> 6);
  int l = threadIdx.x & 63;
  size_t base = (size_t)row * H_ + l * 8;
  short8 ov = *(const short8*)(O + base);
  float x[8];
#pragma unroll
  for (int i = 0; i < 8; ++i) x[i] = bf2f((unsigned short)ov[i]);
  float s = 0.f, q = 0.f;
#pragma unroll
  for (int i = 0; i < 8; ++i) { s += x[i]; q += x[i] * x[i]; }
#pragma unroll
  for (int m = 1; m < 64; m <<= 1) { s += __shfl_xor(s, m); q += __shfl_xor(q, m); }
  float mean = s * (1.f / 512.f);
  float var = q * (1.f / 512.f) - mean * mean;
  float rstd = rsqrtf(var + 1e-6f);
  f32x4 g0 = *(const f32x4*)(g + l * 8), g1v = *(const f32x4*)(g + l * 8 + 4);
  f32x4 b0 = *(const f32x4*)(bvec + l * 8), b1v = *(const f32x4*)(bvec + l * 8 + 4);
  short8 no;
#pragma unroll
  for (int i = 0; i < 4; ++i) {
    no[i]     = (short)f2bf((x[i] - mean) * rstd * g0[i] + b0[i]);
    no[4 + i] = (short)f2bf((x[4 + i] - mean) * rstd * g1v[i] + b1v[i]);
  }
  *(short8*)(nattn + base) = no;
}

// ---------------- LN2(ff bf16) + nattn + text1 -> out ----------------
__global__ __launch_bounds__(256) void k_ln2(const unsigned short* __restrict__ ff,
                                             const unsigned short* __restrict__ nattn,
                                             const float* __restrict__ text1,
                                             const float* __restrict__ g2,
                                             const float* __restrict__ bb2,
                                             float* __restrict__ out) {
  int row = blockIdx.x * 4 + (threadIdx.x >> 6);
  int l = threadIdx.x & 63;
  size_t base = (size_t)row * H_ + l * 8;
  short8 fv = *(const short8*)(ff + base);
  float x[8];
#pragma unroll
  for (int i = 0; i < 8; ++i) x[i] = bf2f((unsigned short)fv[i]);
  float s = 0.f, q = 0.f;
#pragma unroll
  for (int i = 0; i < 8; ++i) { s += x[i]; q += x[i] * x[i]; }
#pragma unroll
  for (int m = 1; m < 64; m <<= 1) { s += __shfl_xor(s, m); q += __shfl_xor(q, m); }
  float mean = s * (1.f / 512.f);
  float var = q * (1.f / 512.f) - mean * mean;
  float rstd = rsqrtf(var + 1e-6f);
  f32x4 g0 = *(const f32x4*)(g2 + l * 8), g1v = *(const f32x4*)(g2 + l * 8 + 4);
  f32x4 b0 = *(const f32x4*)(bb2 + l * 8), b1v = *(const f32x4*)(bb2 + l * 8 + 4);
  short8 nv = *(const short8*)(nattn + base);
  f32x4 t0 = *(const f32x4*)(text1 + base), t1 = *(const f32x4*)(text1 + base + 4);
  f32x4 o0, o1;
#pragma unroll
  for (int i = 0; i < 4; ++i) {
    o0[i] = (x[i] - mean) * rstd * g0[i] + b0[i] + bf2f((unsigned short)nv[i]) + t0[i];
    o1[i] = (x[4 + i] - mean) * rstd * g1v[i] + b1v[i] + bf2f((unsigned short)nv[4 + i]) + t1[i];
  }
  *(f32x4*)(out + base) = o0;
  *(f32x4*)(out + base + 4) = o1;
}

extern "C" void kernel_launch(void* const* d_in, const int* in_sizes, int n_in,
                              void* d_out, int out_size, void* d_ws, size_t ws_size,
                              hipStream_t stream) {
  const float* text1 = (const float*)d_in[0];
  const float* text2 = (const float*)d_in[1];
  // d_in[2] = text1_mask (unused by reference output)
  const int* mask2 = (const int*)d_in[3];
  const float* W1 = (const float*)d_in[4];
  const float* b1 = (const float*)d_in[5];
  const float* W2 = (const float*)d_in[6];
  const float* b2 = (const float*)d_in[7];
  const float* g1 = (const float*)d_in[8];
  const float* bb1 = (const float*)d_in[9];
  const float* g2 = (const float*)d_in[10];
  const float* bb2 = (const float*)d_in[11];

  const size_t MiB = 1024ull * 1024ull;
  char* ws = (char*)d_ws;
  unsigned short* W1T   = (unsigned short*)(ws + 0 * MiB);          // 1 MiB
  unsigned short* W2T   = (unsigned short*)(ws + 1 * MiB);          // 1 MiB
  float*          lbuf  = (float*)(ws + 2 * MiB);                   // 128 KiB
  float*          rq    = (float*)(ws + 2 * MiB + 256 * 1024);      // 128 KiB
  float*          rk    = (float*)(ws + 2 * MiB + 512 * 1024);      // 128 KiB
  unsigned short* qn    = (unsigned short*)(ws + 4 * MiB);    // 32 MiB [4,36)
  unsigned short* kn    = (unsigned short*)(ws + 36 * MiB);   // 32 MiB [36,68)
  unsigned short* vt    = (unsigned short*)(ws + 68 * MiB);   // 32 MiB [68,100)
  unsigned short* P     = (unsigned short*)(ws + 100 * MiB);  // 64 MiB [100,164) (8-batch chunk)
  unsigned short* O     = (unsigned short*)(ws + 164 * MiB);  // 32 MiB [164,196)
  // aliases (phase-ordered lifetimes; every span checked against concurrent readers):
  unsigned short* nattn = (unsigned short*)(ws + 100 * MiB);  // [100,132) over P-lower: P dead after
                                                              //   pass2; nattn live LN1 -> LN2 (!)
  unsigned short* hbuf  = (unsigned short*)(ws + 132 * MiB);  // [132,196) over P-upper + O:
                                                              //   P dead after pass2, O dead after LN1
  unsigned short* ffb   = (unsigned short*)(ws + 4 * MiB);    // [4,36) bf16 over qn: dead after pass1.
                                                              //   MUST NOT overlap nattn [100,132):
                                                              //   LN2 reads nattn AFTER FF2 writes ff
                                                              //   (round-4 NaN bug).
  float* outp = (float*)d_out;

  hipMemsetAsync(lbuf, 0, (size_t)B_ * S1_ * sizeof(float), stream);

  k_cast<<<dim3(B_ * S1_ / 4), 256, 0, stream>>>(text1, qn, rq);
  k_cast<<<dim3(B_ * S2_ / 4), 256, 0, stream>>>(text2, kn, rk);
  k_tw<<<dim3(512 * 1024 / 256), 256, 0, stream>>>(W1, W1T, 9, 1024);
  k_tw<<<dim3(512 * 1024 / 256), 256, 0, stream>>>(W2, W2T, 10, 512);
  k_tvt<<<dim3(H_ / 64, S2_ / 64, B_), 256, 0, stream>>>(kn, vt);

  for (int c = 0; c < 2; ++c) {
    const int c0 = c * 8;
    // pass1: P = exp((qn @ kn^T)*rq*rk - 1) * mask, row sums -> lbuf  [SWZ=0]
    k_gemm<2, 0><<<dim3(S2_ / 128, S1_ / 128, 8), 256, 0, stream>>>(
        qn + (size_t)c0 * S1_ * H_, kn + (size_t)c0 * S2_ * H_,
        nullptr, mask2 + (size_t)c0 * S2_, rq + (size_t)c0 * S1_, rk + (size_t)c0 * S2_,
        lbuf + (size_t)c0 * S1_, P,
        S1_, S2_, H_, (long)S1_ * H_, (long)S2_ * H_, (long)S1_ * S2_);
    // pass2: O = (P @ V) / l   (bf16)  [SWZ=1: vt_z 2 MiB L2-resident per XCD]
    k_gemm<3, 1><<<dim3(H_ / 128, S1_ / 128, 8), 256, 0, stream>>>(
        P, vt + (size_t)c0 * H_ * S2_,
        nullptr, nullptr, nullptr, nullptr,
        lbuf + (size_t)c0 * S1_, O + (size_t)c0 * S1_ * H_,
        S1_, H_, S2_, (long)S1_ * S2_, (long)H_ * S2_, (long)S1_ * H_);
  }

  k_ln1<<<dim3(B_ * S1_ / 4), 256, 0, stream>>>(O, g1, bb1, nattn);
  k_gemm<0, 1><<<dim3(1024 / 128, 32768 / 128, 1), 256, 0, stream>>>(
      nattn, W1T, b1, nullptr, nullptr, nullptr, nullptr, hbuf, 32768, 1024, 512, 0, 0, 0);
  k_gemm<1, 1><<<dim3(512 / 128, 32768 / 128, 1), 256, 0, stream>>>(
      hbuf, W2T, b2, nullptr, nullptr, nullptr, nullptr, ffb, 32768, 512, 1024, 0, 0, 0);
  k_ln2<<<dim3(32768 / 4), 256, 0, stream>>>(ffb, nattn, text1, g2, bb2, outp);
}

// Round 9
// 312.750 us; speedup vs baseline: 1.6580x; 1.1211x over previous
//
#include <hip/hip_runtime.h>
#include <stdint.h>

#define B_ 16
#define S1_ 2048
#define S2_ 2048
#define H_ 512

typedef short short8 __attribute__((ext_vector_type(8)));
typedef float f32x4 __attribute__((ext_vector_type(4)));

__device__ __forceinline__ unsigned short f2bf(float f) {
  unsigned u = __builtin_bit_cast(unsigned, f);
  u += 0x7fffu + ((u >> 16) & 1u);          // round-to-nearest-even
  return (unsigned short)(u >> 16);
}
__device__ __forceinline__ float bf2f(unsigned short us) {
  return __builtin_bit_cast(float, (unsigned)us << 16);
}

__device__ __forceinline__ void gload_lds16(const void* g, void* l) {
  __builtin_amdgcn_global_load_lds((const __attribute__((address_space(1))) void*)g,
                                   (__attribute__((address_space(3))) void*)l,
                                   16, 0, 0);
}

// ---------------- prep: bf16/fp8 cast + reciprocal row-norm ----------------
// WB16: also write bf16 copy. Always writes fp8 (e4m3, raw values) + 1/||row||.
template <int WB16>
__global__ __launch_bounds__(256) void k_cast(const float* __restrict__ x,
                                              unsigned short* __restrict__ y,
                                              unsigned char* __restrict__ y8,
                                              float* __restrict__ rn) {
  int row = blockIdx.x * 4 + (threadIdx.x >> 6);
  int l = threadIdx.x & 63;
  const f32x4* xr = (const f32x4*)(x + (size_t)row * H_) + l * 2;
  f32x4 a = xr[0], b = xr[1];
  float s = a[0]*a[0] + a[1]*a[1] + a[2]*a[2] + a[3]*a[3]
          + b[0]*b[0] + b[1]*b[1] + b[2]*b[2] + b[3]*b[3];
#pragma unroll
  for (int m = 1; m < 64; m <<= 1) s += __shfl_xor(s, m);
  if (l == 0) rn[row] = 1.0f / fmaxf(sqrtf(s), 1e-12f);
  if (WB16) {
    short8 o;
#pragma unroll
    for (int i = 0; i < 4; ++i) { o[i] = (short)f2bf(a[i]); o[4 + i] = (short)f2bf(b[i]); }
    *(short8*)(y + (size_t)row * H_ + l * 8) = o;
  }
  int p0 = __builtin_amdgcn_cvt_pk_fp8_f32(a[0], a[1], 0, false);
  p0 = __builtin_amdgcn_cvt_pk_fp8_f32(a[2], a[3], p0, true);
  int p1 = __builtin_amdgcn_cvt_pk_fp8_f32(b[0], b[1], 0, false);
  p1 = __builtin_amdgcn_cvt_pk_fp8_f32(b[2], b[3], p1, true);
  int2 pk = {p0, p1};
  *(int2*)(y8 + (size_t)row * H_ + l * 8) = pk;
}

// ---------------- prep: transpose+cast weights W[R][C] -> WT[C][R] bf16 ----------------
__global__ __launch_bounds__(256) void k_tw(const float* __restrict__ Wm,
                                            unsigned short* __restrict__ WT,
                                            int lgR, int C) {
  int i = blockIdx.x * 256 + threadIdx.x;     // over C*R outputs
  int R = 1 << lgR;
  int n = i >> lgR, k = i & (R - 1);
  WT[i] = f2bf(Wm[(size_t)k * C + n]);
}

// ---------------- prep: vt[b][h][s] = transpose(kn[b][s][h]) (bf16 -> bf16) ----------------
__global__ __launch_bounds__(256) void k_tvt(const unsigned short* __restrict__ kn,
                                             unsigned short* __restrict__ vt) {
  __shared__ unsigned short tile[64][72];
  int h0 = blockIdx.x * 64, s0 = blockIdx.y * 64, b = blockIdx.z;
  int t = threadIdx.x;
#pragma unroll
  for (int p = 0; p < 2; ++p) {
    int si = p * 32 + (t >> 3);
    int cj = (t & 7) * 8;
    short8 v = *(const short8*)(kn + ((size_t)(b * S2_ + s0 + si)) * H_ + h0 + cj);
#pragma unroll
    for (int x = 0; x < 8; ++x) tile[si][cj + x] = (unsigned short)v[x];
  }
  __syncthreads();
#pragma unroll
  for (int p = 0; p < 2; ++p) {
    int ho = p * 32 + (t >> 3);
    int sx = (t & 7) * 8;
    short8 o;
#pragma unroll
    for (int x = 0; x < 8; ++x) o[x] = (short)tile[sx + x][ho];
    *(short8*)(vt + ((size_t)(b * H_ + h0 + ho)) * S2_ + s0 + sx) = o;
  }
}

// ---------------- MFMA GEMM: 128-row tile, 4 waves, single-buf 32 KiB LDS ----
// Proven structure: stage -> vmcnt(0) -> barrier -> compute -> barrier; high
// blocks/CU residency + cross-block TLP hides staging latency (r3/r5: anything
// that cuts residency loses). FP8=1: A/B are fp8 e4m3, BK=128 -- LDS tile is
// byte-identical (128 rows x 128 B, 16B-granule XOR swizzle) to the bf16
// 128x64 tile, so residency is unchanged while drains and staged bytes halve.
// SWZ: XCD-aware bijective block swizzle; ON for pass2/FF (panel L2 locality),
// OFF for pass1 (measured: concentrates pass1's working set, +10 us).
// MODE 0: FF1 relu(acc+bias) bf16 | MODE 1: FF2 acc+bias bf16
// MODE 2: P=exp(acc*rq[m]*rk[n]-1)*mask bf16 (no rowsum: LN1 is row-scale-
//         invariant, so softmax 1/l is dropped entirely) | MODE 3: acc bf16
template <int MODE, int SWZ, int FP8>
__global__ __launch_bounds__(256, 2) void k_gemm(
    const void* __restrict__ A, const void* __restrict__ BT,
    const float* __restrict__ bias, const int* __restrict__ mask,
    const float* __restrict__ rq, const float* __restrict__ rk,
    void* __restrict__ out,
    int M, int N, int K, long sAbytes, long sBbytes, long sOut) {
  __shared__ char lA[16384];
  __shared__ char lB[16384];

  int bx, by, z;
  if (SWZ) {
    const int gx = gridDim.x, gy = gridDim.y;
    const int nwg = gx * gy * (int)gridDim.z;
    int orig = ((int)blockIdx.z * gy + (int)blockIdx.y) * gx + (int)blockIdx.x;
    int swzid = ((nwg & 7) == 0) ? ((orig & 7) * (nwg >> 3) + (orig >> 3)) : orig;
    z = swzid / (gx * gy);
    int rem = swzid - z * (gx * gy);
    by = rem / gx;
    bx = rem - by * gx;
  } else {
    bx = blockIdx.x; by = blockIdx.y; z = blockIdx.z;
  }

  const int w = threadIdx.x >> 6, l = threadIdx.x & 63;
  const int lr = l & 15, lk = l >> 4;
  const int m0 = by * 128, n0 = bx * 128;
  const int wm = (w >> 1) * 64, wn = (w & 1) * 64;

  // staging: chunk c=j*4+w covers rows 8c..8c+7 (128 B each); lane l covers
  // row 8c+(l>>3), 16 source bytes at col ((l&7)*16) ^ XOR-swizzle; dest linear.
  const size_t rowbytes = (size_t)K * (FP8 ? 1 : 2);
  const int srow = l >> 3;
  const int lswz = ((l & 7) * 16) ^ ((srow & 7) << 4);
  const char* pA = (const char*)A + (size_t)z * sAbytes + (size_t)(m0 + w * 8 + srow) * rowbytes + lswz;
  const char* pB = (const char*)BT + (size_t)z * sBbytes + (size_t)(n0 + w * 8 + srow) * rowbytes + lswz;
  const size_t rstep = rowbytes * 32;   // 32 rows per j-step

  f32x4 acc[4][4];
#pragma unroll
  for (int i = 0; i < 4; ++i)
#pragma unroll
    for (int j = 0; j < 4; ++j) acc[i][j] = (f32x4){0.f, 0.f, 0.f, 0.f};

  const int NT = K >> (FP8 ? 7 : 6);

#pragma unroll 1
  for (int t = 0; t < NT; ++t) {
    const size_t kb = (size_t)t * 128;   // 128 B per tile step in both dtypes
#pragma unroll
    for (int j = 0; j < 4; ++j) {
      gload_lds16(pA + j * rstep + kb, lA + (j * 4 + w) * 1024);
      gload_lds16(pB + j * rstep + kb, lB + (j * 4 + w) * 1024);
    }
    asm volatile("s_waitcnt vmcnt(0)" ::: "memory");
    __syncthreads();
    if (FP8) {
#pragma unroll
      for (int s = 0; s < 4; ++s) {
        long af[4], bf[4];
#pragma unroll
        for (int mi = 0; mi < 4; ++mi) {
          int row = wm + mi * 16 + lr;
          af[mi] = *(const long*)(lA + row * 128 + ((s * 32 + lk * 8) ^ ((row & 7) << 4)));
        }
#pragma unroll
        for (int ni = 0; ni < 4; ++ni) {
          int row = wn + ni * 16 + lr;
          bf[ni] = *(const long*)(lB + row * 128 + ((s * 32 + lk * 8) ^ ((row & 7) << 4)));
        }
#pragma unroll
        for (int mi = 0; mi < 4; ++mi)
#pragma unroll
          for (int ni = 0; ni < 4; ++ni)
            acc[mi][ni] = __builtin_amdgcn_mfma_f32_16x16x32_fp8_fp8(af[mi], bf[ni], acc[mi][ni], 0, 0, 0);
      }
    } else {
      const unsigned short* As = (const unsigned short*)lA;
      const unsigned short* Bs = (const unsigned short*)lB;
#pragma unroll
      for (int s = 0; s < 2; ++s) {
        short8 af[4], bf[4];
#pragma unroll
        for (int mi = 0; mi < 4; ++mi) {
          int row = wm + mi * 16 + lr;
          af[mi] = *(const short8*)(As + row * 64 + ((s * 32 + lk * 8) ^ ((row & 7) << 3)));
        }
#pragma unroll
        for (int ni = 0; ni < 4; ++ni) {
          int row = wn + ni * 16 + lr;
          bf[ni] = *(const short8*)(Bs + row * 64 + ((s * 32 + lk * 8) ^ ((row & 7) << 3)));
        }
#pragma unroll
        for (int mi = 0; mi < 4; ++mi)
#pragma unroll
          for (int ni = 0; ni < 4; ++ni)
            acc[mi][ni] = __builtin_amdgcn_mfma_f32_16x16x32_bf16(af[mi], bf[ni], acc[mi][ni], 0, 0, 0);
      }
    }
    __syncthreads();
  }

  if (MODE == 2) {
    float rqv[4][4], rkv[4], mv[4];
#pragma unroll
    for (int mi = 0; mi < 4; ++mi)
#pragma unroll
      for (int r = 0; r < 4; ++r)
        rqv[mi][r] = rq[(size_t)z * M + m0 + wm + mi * 16 + lk * 4 + r];
#pragma unroll
    for (int ni = 0; ni < 4; ++ni) {
      int gn = n0 + wn + ni * 16 + lr;
      rkv[ni] = rk[(size_t)z * N + gn];
      mv[ni] = (mask[(size_t)z * N + gn] != 0) ? 1.0f : 0.0f;
    }
#pragma unroll
    for (int mi = 0; mi < 4; ++mi)
#pragma unroll
      for (int ni = 0; ni < 4; ++ni) {
        int gn = n0 + wn + ni * 16 + lr;
#pragma unroll
        for (int r = 0; r < 4; ++r) {
          int gm = m0 + wm + mi * 16 + lk * 4 + r;
          float p = __expf(acc[mi][ni][r] * rqv[mi][r] * rkv[ni] - 1.0f) * mv[ni];
          ((unsigned short*)out)[(size_t)z * sOut + (size_t)gm * N + gn] = f2bf(p);
        }
      }
  } else if (MODE == 3) {
#pragma unroll
    for (int mi = 0; mi < 4; ++mi)
#pragma unroll
      for (int r = 0; r < 4; ++r) {
        int gm = m0 + wm + mi * 16 + lk * 4 + r;
#pragma unroll
        for (int ni = 0; ni < 4; ++ni) {
          int gn = n0 + wn + ni * 16 + lr;
          ((unsigned short*)out)[(size_t)z * sOut + (size_t)gm * N + gn] = f2bf(acc[mi][ni][r]);
        }
      }
  } else {
#pragma unroll
    for (int mi = 0; mi < 4; ++mi)
#pragma unroll
      for (int ni = 0; ni < 4; ++ni) {
        int gn = n0 + wn + ni * 16 + lr;
        float bs = bias[gn];
#pragma unroll
        for (int r = 0; r < 4; ++r) {
          int gm = m0 + wm + mi * 16 + lk * 4 + r;
          float v = acc[mi][ni][r] + bs;
          if (MODE == 0) v = fmaxf(v, 0.f);
          ((unsigned short*)out)[(size_t)gm * N + gn] = f2bf(v);
        }
      }
  }
}

// ---------------- LN1: nattn = LN(O)*g+b (bf16); O unnormalized (LN scale-inv) ----
__global__ __launch_bounds__(256) void k_ln1(const unsigned short* __restrict__ O,
                                             const float* __restrict__ g,
                                             const float* __restrict__ bvec,
                                             unsigned short* __restrict__ nattn) {
  int row = blockIdx.x * 4 + (threadIdx.x >> 6);
  int l = threadIdx.x & 63;
  size_t base = (size_t)row * H_ + l * 8;
  short8 ov = *(const short8*)(O + base);
  float x[8];
#pragma unroll
  for (int i = 0; i < 8; ++i) x[i] = bf2f((unsigned short)ov[i]);
  float s = 0.f, q = 0.f;
#pragma unroll
  for (int i = 0; i < 8; ++i) { s += x[i]; q += x[i] * x[i]; }
#pragma unroll
  for (int m = 1; m < 64; m <<= 1) { s += __shfl_xor(s, m); q += __shfl_xor(q, m); }
  float mean = s * (1.f / 512.f);
  float var = q * (1.f / 512.f) - mean * mean;
  float rstd = rsqrtf(var + 1e-6f);
  f32x4 g0 = *(const f32x4*)(g + l * 8), g1v = *(const f32x4*)(g + l * 8 + 4);
  f32x4 b0 = *(const f32x4*)(bvec + l * 8), b1v = *(const f32x4*)(bvec + l * 8 + 4);
  short8 no;
#pragma unroll
  for (int i = 0; i < 4; ++i) {
    no[i]     = (short)f2bf((x[i] - mean) * rstd * g0[i] + b0[i]);
    no[4 + i] = (short)f2bf((x[4 + i] - mean) * rstd * g1v[i] + b1v[i]);
  }
  *(short8*)(nattn + base) = no;
}

// ---------------- LN2(ff bf16) + nattn + text1 -> out ----------------
__global__ __launch_bounds__(256) void k_ln2(const unsigned short* __restrict__ ff,
                                             const unsigned short* __restrict__ nattn,
                                             const float* __restrict__ text1,
                                             const float* __restrict__ g2,
                                             const float* __restrict__ bb2,
                                             float* __restrict__ out) {
  int row = blockIdx.x * 4 + (threadIdx.x >> 6);
  int l = threadIdx.x & 63;
  size_t base = (size_t)row * H_ + l * 8;
  short8 fv = *(const short8*)(ff + base);
  float x[8];
#pragma unroll
  for (int i = 0; i < 8; ++i) x[i] = bf2f((unsigned short)fv[i]);
  float s = 0.f, q = 0.f;
#pragma unroll
  for (int i = 0; i < 8; ++i) { s += x[i]; q += x[i] * x[i]; }
#pragma unroll
  for (int m = 1; m < 64; m <<= 1) { s += __shfl_xor(s, m); q += __shfl_xor(q, m); }
  float mean = s * (1.f / 512.f);
  float var = q * (1.f / 512.f) - mean * mean;
  float rstd = rsqrtf(var + 1e-6f);
  f32x4 g0 = *(const f32x4*)(g2 + l * 8), g1v = *(const f32x4*)(g2 + l * 8 + 4);
  f32x4 b0 = *(const f32x4*)(bb2 + l * 8), b1v = *(const f32x4*)(bb2 + l * 8 + 4);
  short8 nv = *(const short8*)(nattn + base);
  f32x4 t0 = *(const f32x4*)(text1 + base), t1 = *(const f32x4*)(text1 + base + 4);
  f32x4 o0, o1;
#pragma unroll
  for (int i = 0; i < 4; ++i) {
    o0[i] = (x[i] - mean) * rstd * g0[i] + b0[i] + bf2f((unsigned short)nv[i]) + t0[i];
    o1[i] = (x[4 + i] - mean) * rstd * g1v[i] + b1v[i] + bf2f((unsigned short)nv[4 + i]) + t1[i];
  }
  *(f32x4*)(out + base) = o0;
  *(f32x4*)(out + base + 4) = o1;
}

extern "C" void kernel_launch(void* const* d_in, const int* in_sizes, int n_in,
                              void* d_out, int out_size, void* d_ws, size_t ws_size,
                              hipStream_t stream) {
  const float* text1 = (const float*)d_in[0];
  const float* text2 = (const float*)d_in[1];
  // d_in[2] = text1_mask (unused by reference output)
  const int* mask2 = (const int*)d_in[3];
  const float* W1 = (const float*)d_in[4];
  const float* b1 = (const float*)d_in[5];
  const float* W2 = (const float*)d_in[6];
  const float* b2 = (const float*)d_in[7];
  const float* g1 = (const float*)d_in[8];
  const float* bb1 = (const float*)d_in[9];
  const float* g2 = (const float*)d_in[10];
  const float* bb2 = (const float*)d_in[11];

  const size_t MiB = 1024ull * 1024ull;
  char* ws = (char*)d_ws;
  unsigned short* W1T   = (unsigned short*)(ws + 0 * MiB);          // 1 MiB
  unsigned short* W2T   = (unsigned short*)(ws + 1 * MiB);          // 1 MiB
  float*          rq    = (float*)(ws + 2 * MiB);                   // 128 KiB
  float*          rk    = (float*)(ws + 2 * MiB + 256 * 1024);      // 128 KiB
  unsigned char*  qn8   = (unsigned char*)(ws + 4 * MiB);     // 16 MiB [4,20)
  unsigned char*  kn8   = (unsigned char*)(ws + 20 * MiB);    // 16 MiB [20,36)
  unsigned short* kn    = (unsigned short*)(ws + 36 * MiB);   // 32 MiB [36,68)
  unsigned short* vt    = (unsigned short*)(ws + 68 * MiB);   // 32 MiB [68,100)
  unsigned short* P     = (unsigned short*)(ws + 100 * MiB);  // 64 MiB [100,164) (8-batch chunk)
  unsigned short* O     = (unsigned short*)(ws + 164 * MiB);  // 32 MiB [164,196)
  // aliases (phase-ordered lifetimes; every span checked against concurrent readers):
  unsigned short* nattn = (unsigned short*)(ws + 100 * MiB);  // [100,132) over P-lower: P dead after
                                                              //   pass2; nattn live LN1 -> LN2 (!)
  unsigned short* hbuf  = (unsigned short*)(ws + 132 * MiB);  // [132,196) over P-upper + O:
                                                              //   P dead after pass2, O dead after LN1
  unsigned short* ffb   = (unsigned short*)(ws + 4 * MiB);    // [4,36) bf16 over qn8+kn8: dead after
                                                              //   pass1. MUST NOT overlap nattn
                                                              //   [100,132) -- LN2 reads nattn AFTER
                                                              //   FF2 writes ffb (round-4 NaN bug).
  float* outp = (float*)d_out;

  k_cast<0><<<dim3(B_ * S1_ / 4), 256, 0, stream>>>(text1, nullptr, qn8, rq);
  k_cast<1><<<dim3(B_ * S2_ / 4), 256, 0, stream>>>(text2, kn, kn8, rk);
  k_tw<<<dim3(512 * 1024 / 256), 256, 0, stream>>>(W1, W1T, 9, 1024);
  k_tw<<<dim3(512 * 1024 / 256), 256, 0, stream>>>(W2, W2T, 10, 512);
  k_tvt<<<dim3(H_ / 64, S2_ / 64, B_), 256, 0, stream>>>(kn, vt);

  for (int c = 0; c < 2; ++c) {
    const int c0 = c * 8;
    // pass1 (fp8, BK=128): P = exp((q8 @ k8^T)*rq*rk - 1) * mask   [SWZ=0]
    k_gemm<2, 0, 1><<<dim3(S2_ / 128, S1_ / 128, 8), 256, 0, stream>>>(
        qn8 + (size_t)c0 * S1_ * H_, kn8 + (size_t)c0 * S2_ * H_,
        nullptr, mask2 + (size_t)c0 * S2_, rq + (size_t)c0 * S1_, rk + (size_t)c0 * S2_,
        P, S1_, S2_, H_, (long)S1_ * H_, (long)S2_ * H_, (long)S1_ * S2_);
    // pass2 (bf16): O = P @ V (unnormalized -- LN1 washes the row scale)  [SWZ=1]
    k_gemm<3, 1, 0><<<dim3(H_ / 128, S1_ / 128, 8), 256, 0, stream>>>(
        P, vt + (size_t)c0 * H_ * S2_,
        nullptr, nullptr, nullptr, nullptr,
        O + (size_t)c0 * S1_ * H_,
        S1_, H_, S2_, (long)S1_ * S2_ * 2, (long)H_ * S2_ * 2, (long)S1_ * H_);
  }

  k_ln1<<<dim3(B_ * S1_ / 4), 256, 0, stream>>>(O, g1, bb1, nattn);
  k_gemm<0, 1, 0><<<dim3(1024 / 128, 32768 / 128, 1), 256, 0, stream>>>(
      nattn, W1T, b1, nullptr, nullptr, nullptr, hbuf, 32768, 1024, 512, 0, 0, 0);
  k_gemm<1, 1, 0><<<dim3(512 / 128, 32768 / 128, 1), 256, 0, stream>>>(
      hbuf, W2T, b2, nullptr, nullptr, nullptr, ffb, 32768, 512, 1024, 0, 0, 0);
  k_ln2<<<dim3(32768 / 4), 256, 0, stream>>>(ffb, nattn, text1, g2, bb2, outp);
}

// Round 10
// 291.322 us; speedup vs baseline: 1.7800x; 1.0736x over previous
//
#include <hip/hip_runtime.h>
#include <stdint.h>

#define B_ 16
#define S1_ 2048
#define S2_ 2048
#define H_ 512

typedef short short8 __attribute__((ext_vector_type(8)));
typedef float f32x4 __attribute__((ext_vector_type(4)));

__device__ __forceinline__ unsigned short f2bf(float f) {
  unsigned u = __builtin_bit_cast(unsigned, f);
  u += 0x7fffu + ((u >> 16) & 1u);          // round-to-nearest-even
  return (unsigned short)(u >> 16);
}
__device__ __forceinline__ float bf2f(unsigned short us) {
  return __builtin_bit_cast(float, (unsigned)us << 16);
}

__device__ __forceinline__ void gload_lds16(const void* g, void* l) {
  __builtin_amdgcn_global_load_lds((const __attribute__((address_space(1))) void*)g,
                                   (__attribute__((address_space(3))) void*)l,
                                   16, 0, 0);
}

// ---------------- prep: bf16/fp8 cast + reciprocal row-norm ----------------
// WB16: also write bf16 copy. Always writes fp8 (e4m3, raw values) + 1/||row||.
template <int WB16>
__global__ __launch_bounds__(256) void k_cast(const float* __restrict__ x,
                                              unsigned short* __restrict__ y,
                                              unsigned char* __restrict__ y8,
                                              float* __restrict__ rn) {
  int row = blockIdx.x * 4 + (threadIdx.x >> 6);
  int l = threadIdx.x & 63;
  const f32x4* xr = (const f32x4*)(x + (size_t)row * H_) + l * 2;
  f32x4 a = xr[0], b = xr[1];
  float s = a[0]*a[0] + a[1]*a[1] + a[2]*a[2] + a[3]*a[3]
          + b[0]*b[0] + b[1]*b[1] + b[2]*b[2] + b[3]*b[3];
#pragma unroll
  for (int m = 1; m < 64; m <<= 1) s += __shfl_xor(s, m);
  if (l == 0) rn[row] = 1.0f / fmaxf(sqrtf(s), 1e-12f);
  if (WB16) {
    short8 o;
#pragma unroll
    for (int i = 0; i < 4; ++i) { o[i] = (short)f2bf(a[i]); o[4 + i] = (short)f2bf(b[i]); }
    *(short8*)(y + (size_t)row * H_ + l * 8) = o;
  }
  int p0 = __builtin_amdgcn_cvt_pk_fp8_f32(a[0], a[1], 0, false);
  p0 = __builtin_amdgcn_cvt_pk_fp8_f32(a[2], a[3], p0, true);
  int p1 = __builtin_amdgcn_cvt_pk_fp8_f32(b[0], b[1], 0, false);
  p1 = __builtin_amdgcn_cvt_pk_fp8_f32(b[2], b[3], p1, true);
  int2 pk = {p0, p1};
  *(int2*)(y8 + (size_t)row * H_ + l * 8) = pk;
}

// ---------------- prep: transpose+cast weights W[R][C] -> WT[C][R] bf16 ----------------
__global__ __launch_bounds__(256) void k_tw(const float* __restrict__ Wm,
                                            unsigned short* __restrict__ WT,
                                            int lgR, int C) {
  int i = blockIdx.x * 256 + threadIdx.x;     // over C*R outputs
  int R = 1 << lgR;
  int n = i >> lgR, k = i & (R - 1);
  WT[i] = f2bf(Wm[(size_t)k * C + n]);
}

// ---------------- prep: vt[b][h][s] = transpose(kn[b][s][h]) (bf16 -> bf16) ----------------
__global__ __launch_bounds__(256) void k_tvt(const unsigned short* __restrict__ kn,
                                             unsigned short* __restrict__ vt) {
  __shared__ unsigned short tile[64][72];
  int h0 = blockIdx.x * 64, s0 = blockIdx.y * 64, b = blockIdx.z;
  int t = threadIdx.x;
#pragma unroll
  for (int p = 0; p < 2; ++p) {
    int si = p * 32 + (t >> 3);
    int cj = (t & 7) * 8;
    short8 v = *(const short8*)(kn + ((size_t)(b * S2_ + s0 + si)) * H_ + h0 + cj);
#pragma unroll
    for (int x = 0; x < 8; ++x) tile[si][cj + x] = (unsigned short)v[x];
  }
  __syncthreads();
#pragma unroll
  for (int p = 0; p < 2; ++p) {
    int ho = p * 32 + (t >> 3);
    int sx = (t & 7) * 8;
    short8 o;
#pragma unroll
    for (int x = 0; x < 8; ++x) o[x] = (short)tile[sx + x][ho];
    *(short8*)(vt + ((size_t)(b * H_ + h0 + ho)) * S2_ + s0 + sx) = o;
  }
}

// ---------------- MFMA GEMM: 128-row tile, 4 waves, single-buf 32 KiB LDS ----
// Proven structure: stage -> vmcnt(0) -> barrier -> compute -> barrier; high
// blocks/CU residency + cross-block TLP hides staging latency (r3/r5: anything
// that cuts residency loses; r9: pass2 at 2 blk/CU was the slowest dispatch).
// FP8=1: A/B fp8 e4m3, BK=128 -- LDS tile byte-identical to bf16's 128x64.
// SWZ: XCD swizzle; ON for pass2/FF (panel L2 locality), OFF for pass1.
// MODE 0: FF1 relu(acc+bias) bf16 | MODE 1: FF2 acc+bias bf16
// MODE 2: P=exp(acc*rq[m]*rk[n]-1)*mask bf16 (no rowsum: LN1 row-scale-inv)
// MODE 3: acc bf16
template <int MODE, int SWZ, int FP8>
__global__ __launch_bounds__(256, 2) void k_gemm(
    const void* __restrict__ A, const void* __restrict__ BT,
    const float* __restrict__ bias, const int* __restrict__ mask,
    const float* __restrict__ rq, const float* __restrict__ rk,
    void* __restrict__ out,
    int M, int N, int K, long sAbytes, long sBbytes, long sOut) {
  __shared__ char lA[16384];
  __shared__ char lB[16384];

  int bx, by, z;
  if (SWZ) {
    const int gx = gridDim.x, gy = gridDim.y;
    const int nwg = gx * gy * (int)gridDim.z;
    int orig = ((int)blockIdx.z * gy + (int)blockIdx.y) * gx + (int)blockIdx.x;
    int swzid = ((nwg & 7) == 0) ? ((orig & 7) * (nwg >> 3) + (orig >> 3)) : orig;
    z = swzid / (gx * gy);
    int rem = swzid - z * (gx * gy);
    by = rem / gx;
    bx = rem - by * gx;
  } else {
    bx = blockIdx.x; by = blockIdx.y; z = blockIdx.z;
  }

  const int w = threadIdx.x >> 6, l = threadIdx.x & 63;
  const int lr = l & 15, lk = l >> 4;
  const int m0 = by * 128, n0 = bx * 128;
  const int wm = (w >> 1) * 64, wn = (w & 1) * 64;

  // staging: chunk c=j*4+w covers rows 8c..8c+7 (128 B each); lane l covers
  // row 8c+(l>>3), 16 source bytes at col ((l&7)*16) ^ XOR-swizzle; dest linear.
  const size_t rowbytes = (size_t)K * (FP8 ? 1 : 2);
  const int srow = l >> 3;
  const int lswz = ((l & 7) * 16) ^ ((srow & 7) << 4);
  const char* pA = (const char*)A + (size_t)z * sAbytes + (size_t)(m0 + w * 8 + srow) * rowbytes + lswz;
  const char* pB = (const char*)BT + (size_t)z * sBbytes + (size_t)(n0 + w * 8 + srow) * rowbytes + lswz;
  const size_t rstep = rowbytes * 32;   // 32 rows per j-step

  f32x4 acc[4][4];
#pragma unroll
  for (int i = 0; i < 4; ++i)
#pragma unroll
    for (int j = 0; j < 4; ++j) acc[i][j] = (f32x4){0.f, 0.f, 0.f, 0.f};

  const int NT = K >> (FP8 ? 7 : 6);

#pragma unroll 1
  for (int t = 0; t < NT; ++t) {
    const size_t kb = (size_t)t * 128;   // 128 B per tile step in both dtypes
#pragma unroll
    for (int j = 0; j < 4; ++j) {
      gload_lds16(pA + j * rstep + kb, lA + (j * 4 + w) * 1024);
      gload_lds16(pB + j * rstep + kb, lB + (j * 4 + w) * 1024);
    }
    asm volatile("s_waitcnt vmcnt(0)" ::: "memory");
    __syncthreads();
    if (FP8) {
#pragma unroll
      for (int s = 0; s < 4; ++s) {
        long af[4], bf[4];
#pragma unroll
        for (int mi = 0; mi < 4; ++mi) {
          int row = wm + mi * 16 + lr;
          af[mi] = *(const long*)(lA + row * 128 + ((s * 32 + lk * 8) ^ ((row & 7) << 4)));
        }
#pragma unroll
        for (int ni = 0; ni < 4; ++ni) {
          int row = wn + ni * 16 + lr;
          bf[ni] = *(const long*)(lB + row * 128 + ((s * 32 + lk * 8) ^ ((row & 7) << 4)));
        }
#pragma unroll
        for (int mi = 0; mi < 4; ++mi)
#pragma unroll
          for (int ni = 0; ni < 4; ++ni)
            acc[mi][ni] = __builtin_amdgcn_mfma_f32_16x16x32_fp8_fp8(af[mi], bf[ni], acc[mi][ni], 0, 0, 0);
      }
    } else {
      const unsigned short* As = (const unsigned short*)lA;
      const unsigned short* Bs = (const unsigned short*)lB;
#pragma unroll
      for (int s = 0; s < 2; ++s) {
        short8 af[4], bf[4];
#pragma unroll
        for (int mi = 0; mi < 4; ++mi) {
          int row = wm + mi * 16 + lr;
          af[mi] = *(const short8*)(As + row * 64 + ((s * 32 + lk * 8) ^ ((row & 7) << 3)));
        }
#pragma unroll
        for (int ni = 0; ni < 4; ++ni) {
          int row = wn + ni * 16 + lr;
          bf[ni] = *(const short8*)(Bs + row * 64 + ((s * 32 + lk * 8) ^ ((row & 7) << 3)));
        }
#pragma unroll
        for (int mi = 0; mi < 4; ++mi)
#pragma unroll
          for (int ni = 0; ni < 4; ++ni)
            acc[mi][ni] = __builtin_amdgcn_mfma_f32_16x16x32_bf16(af[mi], bf[ni], acc[mi][ni], 0, 0, 0);
      }
    }
    __syncthreads();
  }

  if (MODE == 2) {
    float rqv[4][4], rkv[4], mv[4];
#pragma unroll
    for (int mi = 0; mi < 4; ++mi)
#pragma unroll
      for (int r = 0; r < 4; ++r)
        rqv[mi][r] = rq[(size_t)z * M + m0 + wm + mi * 16 + lk * 4 + r];
#pragma unroll
    for (int ni = 0; ni < 4; ++ni) {
      int gn = n0 + wn + ni * 16 + lr;
      rkv[ni] = rk[(size_t)z * N + gn];
      mv[ni] = (mask[(size_t)z * N + gn] != 0) ? 1.0f : 0.0f;
    }
#pragma unroll
    for (int mi = 0; mi < 4; ++mi)
#pragma unroll
      for (int ni = 0; ni < 4; ++ni) {
        int gn = n0 + wn + ni * 16 + lr;
#pragma unroll
        for (int r = 0; r < 4; ++r) {
          int gm = m0 + wm + mi * 16 + lk * 4 + r;
          float p = __expf(acc[mi][ni][r] * rqv[mi][r] * rkv[ni] - 1.0f) * mv[ni];
          ((unsigned short*)out)[(size_t)z * sOut + (size_t)gm * N + gn] = f2bf(p);
        }
      }
  } else if (MODE == 3) {
#pragma unroll
    for (int mi = 0; mi < 4; ++mi)
#pragma unroll
      for (int r = 0; r < 4; ++r) {
        int gm = m0 + wm + mi * 16 + lk * 4 + r;
#pragma unroll
        for (int ni = 0; ni < 4; ++ni) {
          int gn = n0 + wn + ni * 16 + lr;
          ((unsigned short*)out)[(size_t)z * sOut + (size_t)gm * N + gn] = f2bf(acc[mi][ni][r]);
        }
      }
  } else {
#pragma unroll
    for (int mi = 0; mi < 4; ++mi)
#pragma unroll
      for (int ni = 0; ni < 4; ++ni) {
        int gn = n0 + wn + ni * 16 + lr;
        float bs = bias[gn];
#pragma unroll
        for (int r = 0; r < 4; ++r) {
          int gm = m0 + wm + mi * 16 + lk * 4 + r;
          float v = acc[mi][ni][r] + bs;
          if (MODE == 0) v = fmaxf(v, 0.f);
          ((unsigned short*)out)[(size_t)gm * N + gn] = f2bf(v);
        }
      }
  }
}

// ---------------- LN1: nattn = LN(O)*g+b (bf16); O unnormalized (LN scale-inv) ----
__global__ __launch_bounds__(256) void k_ln1(const unsigned short* __restrict__ O,
                                             const float* __restrict__ g,
                                             const float* __restrict__ bvec,
                                             unsigned short* __restrict__ nattn) {
  int row = blockIdx.x * 4 + (threadIdx.x >> 6);
  int l = threadIdx.x & 63;
  size_t base = (size_t)row * H_ + l * 8;
  short8 ov = *(const short8*)(O + base);
  float x[8];
#pragma unroll
  for (int i = 0; i < 8; ++i) x[i] = bf2f((unsigned short)ov[i]);
  float s = 0.f, q = 0.f;
#pragma unroll
  for (int i = 0; i < 8; ++i) { s += x[i]; q += x[i] * x[i]; }
#pragma unroll
  for (int m = 1; m < 64; m <<= 1) { s += __shfl_xor(s, m); q += __shfl_xor(q, m); }
  float mean = s * (1.f / 512.f);
  float var = q * (1.f / 512.f) - mean * mean;
  float rstd = rsqrtf(var + 1e-6f);
  f32x4 g0 = *(const f32x4*)(g + l * 8), g1v = *(const f32x4*)(g + l * 8 + 4);
  f32x4 b0 = *(const f32x4*)(bvec + l * 8), b1v = *(const f32x4*)(bvec + l * 8 + 4);
  short8 no;
#pragma unroll
  for (int i = 0; i < 4; ++i) {
    no[i]     = (short)f2bf((x[i] - mean) * rstd * g0[i] + b0[i]);
    no[4 + i] = (short)f2bf((x[4 + i] - mean) * rstd * g1v[i] + b1v[i]);
  }
  *(short8*)(nattn + base) = no;
}

// ---------------- LN2(ff bf16) + nattn + text1 -> out ----------------
__global__ __launch_bounds__(256) void k_ln2(const unsigned short* __restrict__ ff,
                                             const unsigned short* __restrict__ nattn,
                                             const float* __restrict__ text1,
                                             const float* __restrict__ g2,
                                             const float* __restrict__ bb2,
                                             float* __restrict__ out) {
  int row = blockIdx.x * 4 + (threadIdx.x >> 6);
  int l = threadIdx.x & 63;
  size_t base = (size_t)row * H_ + l * 8;
  short8 fv = *(const short8*)(ff + base);
  float x[8];
#pragma unroll
  for (int i = 0; i < 8; ++i) x[i] = bf2f((unsigned short)fv[i]);
  float s = 0.f, q = 0.f;
#pragma unroll
  for (int i = 0; i < 8; ++i) { s += x[i]; q += x[i] * x[i]; }
#pragma unroll
  for (int m = 1; m < 64; m <<= 1) { s += __shfl_xor(s, m); q += __shfl_xor(q, m); }
  float mean = s * (1.f / 512.f);
  float var = q * (1.f / 512.f) - mean * mean;
  float rstd = rsqrtf(var + 1e-6f);
  f32x4 g0 = *(const f32x4*)(g2 + l * 8), g1v = *(const f32x4*)(g2 + l * 8 + 4);
  f32x4 b0 = *(const f32x4*)(bb2 + l * 8), b1v = *(const f32x4*)(bb2 + l * 8 + 4);
  short8 nv = *(const short8*)(nattn + base);
  f32x4 t0 = *(const f32x4*)(text1 + base), t1 = *(const f32x4*)(text1 + base + 4);
  f32x4 o0, o1;
#pragma unroll
  for (int i = 0; i < 4; ++i) {
    o0[i] = (x[i] - mean) * rstd * g0[i] + b0[i] + bf2f((unsigned short)nv[i]) + t0[i];
    o1[i] = (x[4 + i] - mean) * rstd * g1v[i] + b1v[i] + bf2f((unsigned short)nv[4 + i]) + t1[i];
  }
  *(f32x4*)(out + base) = o0;
  *(f32x4*)(out + base + 4) = o1;
}

extern "C" void kernel_launch(void* const* d_in, const int* in_sizes, int n_in,
                              void* d_out, int out_size, void* d_ws, size_t ws_size,
                              hipStream_t stream) {
  const float* text1 = (const float*)d_in[0];
  const float* text2 = (const float*)d_in[1];
  // d_in[2] = text1_mask (unused by reference output)
  const int* mask2 = (const int*)d_in[3];
  const float* W1 = (const float*)d_in[4];
  const float* b1 = (const float*)d_in[5];
  const float* W2 = (const float*)d_in[6];
  const float* b2 = (const float*)d_in[7];
  const float* g1 = (const float*)d_in[8];
  const float* bb1 = (const float*)d_in[9];
  const float* g2 = (const float*)d_in[10];
  const float* bb2 = (const float*)d_in[11];

  const size_t MiB = 1024ull * 1024ull;
  char* ws = (char*)d_ws;
  // ---- layout (max offset 196 MiB, same as prior rounds) ----
  unsigned short* W1T   = (unsigned short*)(ws + 0 * MiB);          // 1 MiB
  unsigned short* W2T   = (unsigned short*)(ws + 1 * MiB);          // 1 MiB
  float*          rq    = (float*)(ws + 2 * MiB);                   // 128 KiB
  float*          rk    = (float*)(ws + 2 * MiB + 256 * 1024);      // 128 KiB
  unsigned char*  qn8   = (unsigned char*)(ws + 4 * MiB);     // 16 MiB [4,20)
  unsigned char*  kn8   = (unsigned char*)(ws + 20 * MiB);    // 16 MiB [20,36)
  unsigned short* kn    = (unsigned short*)(ws + 36 * MiB);   // 32 MiB [36,68): dead after k_tvt
  unsigned short* vt    = (unsigned short*)(ws + 164 * MiB);  // 32 MiB [164,196): dead after pass2
  unsigned short* P     = (unsigned short*)(ws + 36 * MiB);   // 128 MiB [36,164) over kn (dead);
                                                              //   all 16 batches, dead after pass2
  unsigned short* O     = (unsigned short*)(ws + 4 * MiB);    // 32 MiB [4,36) over qn8+kn8 (dead
                                                              //   after pass1; pass2 runs later)
  // aliases (stream-order lifetimes; each span checked against later readers):
  unsigned short* nattn = (unsigned short*)(ws + 100 * MiB);  // [100,132) over P-mid (dead after
                                                              //   pass2); live LN1 -> LN2; nothing
                                                              //   writes [100,132) in between (FF1
                                                              //   -> [132,196), FF2 -> [36,68)).
  unsigned short* hbuf  = (unsigned short*)(ws + 132 * MiB);  // [132,196) over P-upper + vt (both
                                                              //   dead after pass2)
  unsigned short* ffb   = (unsigned short*)(ws + 36 * MiB);   // [36,68) over P-lower (dead); NOT
                                                              //   overlapping nattn (round-4 bug)
  float* outp = (float*)d_out;

  k_cast<0><<<dim3(B_ * S1_ / 4), 256, 0, stream>>>(text1, nullptr, qn8, rq);
  k_cast<1><<<dim3(B_ * S2_ / 4), 256, 0, stream>>>(text2, kn, kn8, rk);
  k_tw<<<dim3(512 * 1024 / 256), 256, 0, stream>>>(W1, W1T, 9, 1024);
  k_tw<<<dim3(512 * 1024 / 256), 256, 0, stream>>>(W2, W2T, 10, 512);
  k_tvt<<<dim3(H_ / 64, S2_ / 64, B_), 256, 0, stream>>>(kn, vt);

  // pass1 (fp8, BK=128), all 16 batches: P = exp((q8 @ k8^T)*rq*rk - 1) * mask [SWZ=0]
  k_gemm<2, 0, 1><<<dim3(S2_ / 128, S1_ / 128, B_), 256, 0, stream>>>(
      qn8, kn8, nullptr, mask2, rq, rk,
      P, S1_, S2_, H_, (long)S1_ * H_, (long)S2_ * H_, (long)S1_ * S2_);
  // pass2 (bf16), all 16 batches: O = P @ V (unnormalized; LN1 washes row scale)
  // grid 4x16x16 = 1024 blocks = 4 blk/CU (r9: 512 blocks = 2/CU was the bottleneck)
  k_gemm<3, 1, 0><<<dim3(H_ / 128, S1_ / 128, B_), 256, 0, stream>>>(
      P, vt, nullptr, nullptr, nullptr, nullptr,
      O, S1_, H_, S2_, (long)S1_ * S2_ * 2, (long)H_ * S2_ * 2, (long)S1_ * H_);

  k_ln1<<<dim3(B_ * S1_ / 4), 256, 0, stream>>>(O, g1, bb1, nattn);
  k_gemm<0, 1, 0><<<dim3(1024 / 128, 32768 / 128, 1), 256, 0, stream>>>(
      nattn, W1T, b1, nullptr, nullptr, nullptr, hbuf, 32768, 1024, 512, 0, 0, 0);
  k_gemm<1, 1, 0><<<dim3(512 / 128, 32768 / 128, 1), 256, 0, stream>>>(
      hbuf, W2T, b2, nullptr, nullptr, nullptr, ffb, 32768, 512, 1024, 0, 0, 0);
  k_ln2<<<dim3(32768 / 4), 256, 0, stream>>>(ffb, nattn, text1, g2, bb2, outp);
}

// Round 11
// 289.086 us; speedup vs baseline: 1.7937x; 1.0077x over previous
//
#include <hip/hip_runtime.h>
#include <stdint.h>

#define B_ 16
#define S1_ 2048
#define S2_ 2048
#define H_ 512

typedef short short8 __attribute__((ext_vector_type(8)));
typedef float f32x4 __attribute__((ext_vector_type(4)));
typedef long long2v __attribute__((ext_vector_type(2)));

__device__ __forceinline__ unsigned short f2bf(float f) {
  unsigned u = __builtin_bit_cast(unsigned, f);
  u += 0x7fffu + ((u >> 16) & 1u);          // round-to-nearest-even
  return (unsigned short)(u >> 16);
}
__device__ __forceinline__ float bf2f(unsigned short us) {
  return __builtin_bit_cast(float, (unsigned)us << 16);
}

__device__ __forceinline__ void gload_lds16(const void* g, void* l) {
  __builtin_amdgcn_global_load_lds((const __attribute__((address_space(1))) void*)g,
                                   (__attribute__((address_space(3))) void*)l,
                                   16, 0, 0);
}

// ---------------- prep: bf16/fp8 cast + reciprocal row-norm ----------------
// WB16: also write bf16 copy. fp8 (e4m3) is stored PERMUTED within each
// 128-byte K-block: b' = lk*32 + s*8 + j for orig b = s*32 + lk*8 + j.
// This makes a lane's s and s+1 MFMA fragments adjacent in LDS, enabling
// conflict-free ds_read_b128 in the GEMM (8B reads vs 16B XOR granule was a
// 2x LDS serialization: 8.4M SQ_LDS_BANK_CONFLICT/dispatch in r10).
template <int WB16>
__global__ __launch_bounds__(256) void k_cast(const float* __restrict__ x,
                                              unsigned short* __restrict__ y,
                                              unsigned char* __restrict__ y8,
                                              float* __restrict__ rn) {
  int row = blockIdx.x * 4 + (threadIdx.x >> 6);
  int l = threadIdx.x & 63;
  const f32x4* xr = (const f32x4*)(x + (size_t)row * H_) + l * 2;
  f32x4 a = xr[0], b = xr[1];
  float s = a[0]*a[0] + a[1]*a[1] + a[2]*a[2] + a[3]*a[3]
          + b[0]*b[0] + b[1]*b[1] + b[2]*b[2] + b[3]*b[3];
#pragma unroll
  for (int m = 1; m < 64; m <<= 1) s += __shfl_xor(s, m);
  if (l == 0) rn[row] = 1.0f / fmaxf(sqrtf(s), 1e-12f);
  if (WB16) {
    short8 o;
#pragma unroll
    for (int i = 0; i < 4; ++i) { o[i] = (short)f2bf(a[i]); o[4 + i] = (short)f2bf(b[i]); }
    *(short8*)(y + (size_t)row * H_ + l * 8) = o;
  }
  int p0 = __builtin_amdgcn_cvt_pk_fp8_f32(a[0], a[1], 0, false);
  p0 = __builtin_amdgcn_cvt_pk_fp8_f32(a[2], a[3], p0, true);
  int p1 = __builtin_amdgcn_cvt_pk_fp8_f32(b[0], b[1], 0, false);
  p1 = __builtin_amdgcn_cvt_pk_fp8_f32(b[2], b[3], p1, true);
  int2 pk = {p0, p1};
  // lane l covers orig bytes [l*8, l*8+8): t=l>>4 (128B block), s=(l>>2)&3, lk=l&3
  int poff = ((l >> 4) * 128) + ((l & 3) * 32) + (((l >> 2) & 3) * 8);
  *(int2*)(y8 + (size_t)row * H_ + poff) = pk;
}

// ---------------- prep: transpose+cast weights W[R][C] -> WT[C][R] bf16 ----------------
__global__ __launch_bounds__(256) void k_tw(const float* __restrict__ Wm,
                                            unsigned short* __restrict__ WT,
                                            int lgR, int C) {
  int i = blockIdx.x * 256 + threadIdx.x;     // over C*R outputs
  int R = 1 << lgR;
  int n = i >> lgR, k = i & (R - 1);
  WT[i] = f2bf(Wm[(size_t)k * C + n]);
}

// ---------------- prep: vt[b][h][s] = transpose(kn[b][s][h]) (bf16 -> bf16) ----------------
__global__ __launch_bounds__(256) void k_tvt(const unsigned short* __restrict__ kn,
                                             unsigned short* __restrict__ vt) {
  __shared__ unsigned short tile[64][72];
  int h0 = blockIdx.x * 64, s0 = blockIdx.y * 64, b = blockIdx.z;
  int t = threadIdx.x;
#pragma unroll
  for (int p = 0; p < 2; ++p) {
    int si = p * 32 + (t >> 3);
    int cj = (t & 7) * 8;
    short8 v = *(const short8*)(kn + ((size_t)(b * S2_ + s0 + si)) * H_ + h0 + cj);
#pragma unroll
    for (int x = 0; x < 8; ++x) tile[si][cj + x] = (unsigned short)v[x];
  }
  __syncthreads();
#pragma unroll
  for (int p = 0; p < 2; ++p) {
    int ho = p * 32 + (t >> 3);
    int sx = (t & 7) * 8;
    short8 o;
#pragma unroll
    for (int x = 0; x < 8; ++x) o[x] = (short)tile[sx + x][ho];
    *(short8*)(vt + ((size_t)(b * H_ + h0 + ho)) * S2_ + s0 + sx) = o;
  }
}

// ---------------- MFMA GEMM: 128-row tile, 4 waves, single-buf 32 KiB LDS ----
// Proven structure: stage -> vmcnt(0) -> barrier -> compute -> barrier; high
// blocks/CU residency + cross-block TLP hides staging latency (r3/r5: anything
// that cuts residency loses; r9: pass2 at 2 blk/CU was the slowest dispatch).
// FP8=1: A/B fp8 e4m3 in (s,lk)-permuted layout (see k_cast), BK=128; reads
// are ds_read_b128 matching the 16B XOR granule -> conflict-free (r10 fix).
// SWZ: XCD swizzle; ON for pass2/FF (panel L2 locality), OFF for pass1.
// MODE 0: FF1 relu(acc+bias) bf16 | MODE 1: FF2 acc+bias bf16
// MODE 2: P=exp(acc*rq[m]*rk[n]-1)*mask bf16 (no rowsum: LN1 row-scale-inv)
// MODE 3: acc bf16
template <int MODE, int SWZ, int FP8>
__global__ __launch_bounds__(256, 2) void k_gemm(
    const void* __restrict__ A, const void* __restrict__ BT,
    const float* __restrict__ bias, const int* __restrict__ mask,
    const float* __restrict__ rq, const float* __restrict__ rk,
    void* __restrict__ out,
    int M, int N, int K, long sAbytes, long sBbytes, long sOut) {
  __shared__ char lA[16384];
  __shared__ char lB[16384];

  int bx, by, z;
  if (SWZ) {
    const int gx = gridDim.x, gy = gridDim.y;
    const int nwg = gx * gy * (int)gridDim.z;
    int orig = ((int)blockIdx.z * gy + (int)blockIdx.y) * gx + (int)blockIdx.x;
    int swzid = ((nwg & 7) == 0) ? ((orig & 7) * (nwg >> 3) + (orig >> 3)) : orig;
    z = swzid / (gx * gy);
    int rem = swzid - z * (gx * gy);
    by = rem / gx;
    bx = rem - by * gx;
  } else {
    bx = blockIdx.x; by = blockIdx.y; z = blockIdx.z;
  }

  const int w = threadIdx.x >> 6, l = threadIdx.x & 63;
  const int lr = l & 15, lk = l >> 4;
  const int m0 = by * 128, n0 = bx * 128;
  const int wm = (w >> 1) * 64, wn = (w & 1) * 64;

  // staging: chunk c=j*4+w covers rows 8c..8c+7 (128 B each); lane l covers
  // row 8c+(l>>3), 16 source bytes at col ((l&7)*16) ^ XOR-swizzle; dest linear.
  const size_t rowbytes = (size_t)K * (FP8 ? 1 : 2);
  const int srow = l >> 3;
  const int lswz = ((l & 7) * 16) ^ ((srow & 7) << 4);
  const char* pA = (const char*)A + (size_t)z * sAbytes + (size_t)(m0 + w * 8 + srow) * rowbytes + lswz;
  const char* pB = (const char*)BT + (size_t)z * sBbytes + (size_t)(n0 + w * 8 + srow) * rowbytes + lswz;
  const size_t rstep = rowbytes * 32;   // 32 rows per j-step

  f32x4 acc[4][4];
#pragma unroll
  for (int i = 0; i < 4; ++i)
#pragma unroll
    for (int j = 0; j < 4; ++j) acc[i][j] = (f32x4){0.f, 0.f, 0.f, 0.f};

  const int NT = K >> (FP8 ? 7 : 6);

#pragma unroll 1
  for (int t = 0; t < NT; ++t) {
    const size_t kb = (size_t)t * 128;   // 128 B per tile step in both dtypes
#pragma unroll
    for (int j = 0; j < 4; ++j) {
      gload_lds16(pA + j * rstep + kb, lA + (j * 4 + w) * 1024);
      gload_lds16(pB + j * rstep + kb, lB + (j * 4 + w) * 1024);
    }
    asm volatile("s_waitcnt vmcnt(0)" ::: "memory");
    __syncthreads();
    if (FP8) {
      // permuted layout: one b128 at (lk*32 + s2*16) ^ swz holds the s=2*s2
      // (.x) and s=2*s2+1 (.y) fragments; slot=(lk*2+s2)^(lr&7) spans all 8
      // 16B slots per quarter-wave -> conflict-free.
#pragma unroll
      for (int s2 = 0; s2 < 2; ++s2) {
        long2v af[4], bf[4];
#pragma unroll
        for (int mi = 0; mi < 4; ++mi) {
          int row = wm + mi * 16 + lr;
          af[mi] = *(const long2v*)(lA + row * 128 + ((lk * 32 + s2 * 16) ^ ((row & 7) << 4)));
        }
#pragma unroll
        for (int ni = 0; ni < 4; ++ni) {
          int row = wn + ni * 16 + lr;
          bf[ni] = *(const long2v*)(lB + row * 128 + ((lk * 32 + s2 * 16) ^ ((row & 7) << 4)));
        }
#pragma unroll
        for (int mi = 0; mi < 4; ++mi)
#pragma unroll
          for (int ni = 0; ni < 4; ++ni) {
            acc[mi][ni] = __builtin_amdgcn_mfma_f32_16x16x32_fp8_fp8(af[mi].x, bf[ni].x, acc[mi][ni], 0, 0, 0);
            acc[mi][ni] = __builtin_amdgcn_mfma_f32_16x16x32_fp8_fp8(af[mi].y, bf[ni].y, acc[mi][ni], 0, 0, 0);
          }
      }
    } else {
      const unsigned short* As = (const unsigned short*)lA;
      const unsigned short* Bs = (const unsigned short*)lB;
#pragma unroll
      for (int s = 0; s < 2; ++s) {
        short8 af[4], bf[4];
#pragma unroll
        for (int mi = 0; mi < 4; ++mi) {
          int row = wm + mi * 16 + lr;
          af[mi] = *(const short8*)(As + row * 64 + ((s * 32 + lk * 8) ^ ((row & 7) << 3)));
        }
#pragma unroll
        for (int ni = 0; ni < 4; ++ni) {
          int row = wn + ni * 16 + lr;
          bf[ni] = *(const short8*)(Bs + row * 64 + ((s * 32 + lk * 8) ^ ((row & 7) << 3)));
        }
#pragma unroll
        for (int mi = 0; mi < 4; ++mi)
#pragma unroll
          for (int ni = 0; ni < 4; ++ni)
            acc[mi][ni] = __builtin_amdgcn_mfma_f32_16x16x32_bf16(af[mi], bf[ni], acc[mi][ni], 0, 0, 0);
      }
    }
    __syncthreads();
  }

  if (MODE == 2) {
    float rqv[4][4], rkv[4], mv[4];
#pragma unroll
    for (int mi = 0; mi < 4; ++mi)
#pragma unroll
      for (int r = 0; r < 4; ++r)
        rqv[mi][r] = rq[(size_t)z * M + m0 + wm + mi * 16 + lk * 4 + r];
#pragma unroll
    for (int ni = 0; ni < 4; ++ni) {
      int gn = n0 + wn + ni * 16 + lr;
      rkv[ni] = rk[(size_t)z * N + gn];
      mv[ni] = (mask[(size_t)z * N + gn] != 0) ? 1.0f : 0.0f;
    }
#pragma unroll
    for (int mi = 0; mi < 4; ++mi)
#pragma unroll
      for (int ni = 0; ni < 4; ++ni) {
        int gn = n0 + wn + ni * 16 + lr;
#pragma unroll
        for (int r = 0; r < 4; ++r) {
          int gm = m0 + wm + mi * 16 + lk * 4 + r;
          float p = __expf(acc[mi][ni][r] * rqv[mi][r] * rkv[ni] - 1.0f) * mv[ni];
          ((unsigned short*)out)[(size_t)z * sOut + (size_t)gm * N + gn] = f2bf(p);
        }
      }
  } else if (MODE == 3) {
#pragma unroll
    for (int mi = 0; mi < 4; ++mi)
#pragma unroll
      for (int r = 0; r < 4; ++r) {
        int gm = m0 + wm + mi * 16 + lk * 4 + r;
#pragma unroll
        for (int ni = 0; ni < 4; ++ni) {
          int gn = n0 + wn + ni * 16 + lr;
          ((unsigned short*)out)[(size_t)z * sOut + (size_t)gm * N + gn] = f2bf(acc[mi][ni][r]);
        }
      }
  } else {
#pragma unroll
    for (int mi = 0; mi < 4; ++mi)
#pragma unroll
      for (int ni = 0; ni < 4; ++ni) {
        int gn = n0 + wn + ni * 16 + lr;
        float bs = bias[gn];
#pragma unroll
        for (int r = 0; r < 4; ++r) {
          int gm = m0 + wm + mi * 16 + lk * 4 + r;
          float v = acc[mi][ni][r] + bs;
          if (MODE == 0) v = fmaxf(v, 0.f);
          ((unsigned short*)out)[(size_t)gm * N + gn] = f2bf(v);
        }
      }
  }
}

// ---------------- LN1: nattn = LN(O)*g+b (bf16); O unnormalized (LN scale-inv) ----
__global__ __launch_bounds__(256) void k_ln1(const unsigned short* __restrict__ O,
                                             const float* __restrict__ g,
                                             const float* __restrict__ bvec,
                                             unsigned short* __restrict__ nattn) {
  int row = blockIdx.x * 4 + (threadIdx.x >> 6);
  int l = threadIdx.x & 63;
  size_t base = (size_t)row * H_ + l * 8;
  short8 ov = *(const short8*)(O + base);
  float x[8];
#pragma unroll
  for (int i = 0; i < 8; ++i) x[i] = bf2f((unsigned short)ov[i]);
  float s = 0.f, q = 0.f;
#pragma unroll
  for (int i = 0; i < 8; ++i) { s += x[i]; q += x[i] * x[i]; }
#pragma unroll
  for (int m = 1; m < 64; m <<= 1) { s += __shfl_xor(s, m); q += __shfl_xor(q, m); }
  float mean = s * (1.f / 512.f);
  float var = q * (1.f / 512.f) - mean * mean;
  float rstd = rsqrtf(var + 1e-6f);
  f32x4 g0 = *(const f32x4*)(g + l * 8), g1v = *(const f32x4*)(g + l * 8 + 4);
  f32x4 b0 = *(const f32x4*)(bvec + l * 8), b1v = *(const f32x4*)(bvec + l * 8 + 4);
  short8 no;
#pragma unroll
  for (int i = 0; i < 4; ++i) {
    no[i]     = (short)f2bf((x[i] - mean) * rstd * g0[i] + b0[i]);
    no[4 + i] = (short)f2bf((x[4 + i] - mean) * rstd * g1v[i] + b1v[i]);
  }
  *(short8*)(nattn + base) = no;
}

// ---------------- LN2(ff bf16) + nattn + text1 -> out ----------------
__global__ __launch_bounds__(256) void k_ln2(const unsigned short* __restrict__ ff,
                                             const unsigned short* __restrict__ nattn,
                                             const float* __restrict__ text1,
                                             const float* __restrict__ g2,
                                             const float* __restrict__ bb2,
                                             float* __restrict__ out) {
  int row = blockIdx.x * 4 + (threadIdx.x >> 6);
  int l = threadIdx.x & 63;
  size_t base = (size_t)row * H_ + l * 8;
  short8 fv = *(const short8*)(ff + base);
  float x[8];
#pragma unroll
  for (int i = 0; i < 8; ++i) x[i] = bf2f((unsigned short)fv[i]);
  float s = 0.f, q = 0.f;
#pragma unroll
  for (int i = 0; i < 8; ++i) { s += x[i]; q += x[i] * x[i]; }
#pragma unroll
  for (int m = 1; m < 64; m <<= 1) { s += __shfl_xor(s, m); q += __shfl_xor(q, m); }
  float mean = s * (1.f / 512.f);
  float var = q * (1.f / 512.f) - mean * mean;
  float rstd = rsqrtf(var + 1e-6f);
  f32x4 g0 = *(const f32x4*)(g2 + l * 8), g1v = *(const f32x4*)(g2 + l * 8 + 4);
  f32x4 b0 = *(const f32x4*)(bb2 + l * 8), b1v = *(const f32x4*)(bb2 + l * 8 + 4);
  short8 nv = *(const short8*)(nattn + base);
  f32x4 t0 = *(const f32x4*)(text1 + base), t1 = *(const f32x4*)(text1 + base + 4);
  f32x4 o0, o1;
#pragma unroll
  for (int i = 0; i < 4; ++i) {
    o0[i] = (x[i] - mean) * rstd * g0[i] + b0[i] + bf2f((unsigned short)nv[i]) + t0[i];
    o1[i] = (x[4 + i] - mean) * rstd * g1v[i] + b1v[i] + bf2f((unsigned short)nv[4 + i]) + t1[i];
  }
  *(f32x4*)(out + base) = o0;
  *(f32x4*)(out + base + 4) = o1;
}

extern "C" void kernel_launch(void* const* d_in, const int* in_sizes, int n_in,
                              void* d_out, int out_size, void* d_ws, size_t ws_size,
                              hipStream_t stream) {
  const float* text1 = (const float*)d_in[0];
  const float* text2 = (const float*)d_in[1];
  // d_in[2] = text1_mask (unused by reference output)
  const int* mask2 = (const int*)d_in[3];
  const float* W1 = (const float*)d_in[4];
  const float* b1 = (const float*)d_in[5];
  const float* W2 = (const float*)d_in[6];
  const float* b2 = (const float*)d_in[7];
  const float* g1 = (const float*)d_in[8];
  const float* bb1 = (const float*)d_in[9];
  const float* g2 = (const float*)d_in[10];
  const float* bb2 = (const float*)d_in[11];

  const size_t MiB = 1024ull * 1024ull;
  char* ws = (char*)d_ws;
  // ---- layout (max offset 196 MiB) ----
  unsigned short* W1T   = (unsigned short*)(ws + 0 * MiB);          // 1 MiB
  unsigned short* W2T   = (unsigned short*)(ws + 1 * MiB);          // 1 MiB
  float*          rq    = (float*)(ws + 2 * MiB);                   // 128 KiB
  float*          rk    = (float*)(ws + 2 * MiB + 256 * 1024);      // 128 KiB
  unsigned char*  qn8   = (unsigned char*)(ws + 4 * MiB);     // 16 MiB [4,20)
  unsigned char*  kn8   = (unsigned char*)(ws + 20 * MiB);    // 16 MiB [20,36)
  unsigned short* kn    = (unsigned short*)(ws + 36 * MiB);   // 32 MiB [36,68): dead after k_tvt
  unsigned short* vt    = (unsigned short*)(ws + 164 * MiB);  // 32 MiB [164,196): dead after pass2
  unsigned short* P     = (unsigned short*)(ws + 36 * MiB);   // 128 MiB [36,164) over kn (dead);
                                                              //   all 16 batches, dead after pass2
  unsigned short* O     = (unsigned short*)(ws + 4 * MiB);    // 32 MiB [4,36) over qn8+kn8 (dead
                                                              //   after pass1; pass2 runs later)
  // aliases (stream-order lifetimes; each span checked against later readers):
  unsigned short* nattn = (unsigned short*)(ws + 100 * MiB);  // [100,132) over P-mid (dead after
                                                              //   pass2); live LN1 -> LN2; nothing
                                                              //   writes [100,132) in between (FF1
                                                              //   -> [132,196), FF2 -> [36,68)).
  unsigned short* hbuf  = (unsigned short*)(ws + 132 * MiB);  // [132,196) over P-upper + vt (both
                                                              //   dead after pass2)
  unsigned short* ffb   = (unsigned short*)(ws + 36 * MiB);   // [36,68) over P-lower (dead); NOT
                                                              //   overlapping nattn (round-4 bug)
  float* outp = (float*)d_out;

  k_cast<0><<<dim3(B_ * S1_ / 4), 256, 0, stream>>>(text1, nullptr, qn8, rq);
  k_cast<1><<<dim3(B_ * S2_ / 4), 256, 0, stream>>>(text2, kn, kn8, rk);
  k_tw<<<dim3(512 * 1024 / 256), 256, 0, stream>>>(W1, W1T, 9, 1024);
  k_tw<<<dim3(512 * 1024 / 256), 256, 0, stream>>>(W2, W2T, 10, 512);
  k_tvt<<<dim3(H_ / 64, S2_ / 64, B_), 256, 0, stream>>>(kn, vt);

  // pass1 (fp8 permuted, BK=128), all 16 batches: P = exp((q8@k8^T)*rq*rk - 1)*mask [SWZ=0]
  k_gemm<2, 0, 1><<<dim3(S2_ / 128, S1_ / 128, B_), 256, 0, stream>>>(
      qn8, kn8, nullptr, mask2, rq, rk,
      P, S1_, S2_, H_, (long)S1_ * H_, (long)S2_ * H_, (long)S1_ * S2_);
  // pass2 (bf16), all 16 batches: O = P @ V (unnormalized; LN1 washes row scale)
  // grid 4x16x16 = 1024 blocks = 4 blk/CU (r9: 512 blocks = 2/CU was the bottleneck)
  k_gemm<3, 1, 0><<<dim3(H_ / 128, S1_ / 128, B_), 256, 0, stream>>>(
      P, vt, nullptr, nullptr, nullptr, nullptr,
      O, S1_, H_, S2_, (long)S1_ * S2_ * 2, (long)H_ * S2_ * 2, (long)S1_ * H_);

  k_ln1<<<dim3(B_ * S1_ / 4), 256, 0, stream>>>(O, g1, bb1, nattn);
  k_gemm<0, 1, 0><<<dim3(1024 / 128, 32768 / 128, 1), 256, 0, stream>>>(
      nattn, W1T, b1, nullptr, nullptr, nullptr, hbuf, 32768, 1024, 512, 0, 0, 0);
  k_gemm<1, 1, 0><<<dim3(512 / 128, 32768 / 128, 1), 256, 0, stream>>>(
      hbuf, W2T, b2, nullptr, nullptr, nullptr, ffb, 32768, 512, 1024, 0, 0, 0);
  k_ln2<<<dim3(32768 / 4), 256, 0, stream>>>(ffb, nattn, text1, g2, bb2, outp);
}

// Round 13
// 288.718 us; speedup vs baseline: 1.7960x; 1.0013x over previous
//
#include <hip/hip_runtime.h>
#include <stdint.h>

#define B_ 16
#define S1_ 2048
#define S2_ 2048
#define H_ 512

typedef short short8 __attribute__((ext_vector_type(8)));
typedef float f32x4 __attribute__((ext_vector_type(4)));
typedef long long2v __attribute__((ext_vector_type(2)));

__device__ __forceinline__ unsigned short f2bf(float f) {
  unsigned u = __builtin_bit_cast(unsigned, f);
  u += 0x7fffu + ((u >> 16) & 1u);          // round-to-nearest-even
  return (unsigned short)(u >> 16);
}
__device__ __forceinline__ float bf2f(unsigned short us) {
  return __builtin_bit_cast(float, (unsigned)us << 16);
}

__device__ __forceinline__ void gload_lds16(const void* g, void* l) {
  __builtin_amdgcn_global_load_lds((const __attribute__((address_space(1))) void*)g,
                                   (__attribute__((address_space(3))) void*)l,
                                   16, 0, 0);
}

// ---------------- prep: bf16/fp8 cast + reciprocal row-norm ----------------
// WB16: also write bf16 copy. fp8 (e4m3) stored PERMUTED within each 128-byte
// K-block: b' = lk*32 + s*8 + j for orig b = s*32 + lk*8 + j -- a lane's two
// 8B MFMA fragments become ADJACENT, enabling one 16B LDS read per fragment
// pair (16B granularity matches the XOR swizzle -> conflict-free).
// NOTE (r12 lesson): fp8 is ONLY valid for the QK^T operands -- unit-norm rows
// bound the ABSOLUTE score error (eps/sqrt(512)); P/V/FF have no absolute
// bound, their ~2-6% RELATIVE error does NOT average down and blows absmax.
template <int WB16>
__global__ __launch_bounds__(256) void k_cast(const float* __restrict__ x,
                                              unsigned short* __restrict__ y,
                                              unsigned char* __restrict__ y8,
                                              float* __restrict__ rn) {
  int row = blockIdx.x * 4 + (threadIdx.x >> 6);
  int l = threadIdx.x & 63;
  const f32x4* xr = (const f32x4*)(x + (size_t)row * H_) + l * 2;
  f32x4 a = xr[0], b = xr[1];
  float s = a[0]*a[0] + a[1]*a[1] + a[2]*a[2] + a[3]*a[3]
          + b[0]*b[0] + b[1]*b[1] + b[2]*b[2] + b[3]*b[3];
#pragma unroll
  for (int m = 1; m < 64; m <<= 1) s += __shfl_xor(s, m);
  if (l == 0) rn[row] = 1.0f / fmaxf(sqrtf(s), 1e-12f);
  if (WB16) {
    short8 o;
#pragma unroll
    for (int i = 0; i < 4; ++i) { o[i] = (short)f2bf(a[i]); o[4 + i] = (short)f2bf(b[i]); }
    *(short8*)(y + (size_t)row * H_ + l * 8) = o;
  }
  int p0 = __builtin_amdgcn_cvt_pk_fp8_f32(a[0], a[1], 0, false);
  p0 = __builtin_amdgcn_cvt_pk_fp8_f32(a[2], a[3], p0, true);
  int p1 = __builtin_amdgcn_cvt_pk_fp8_f32(b[0], b[1], 0, false);
  p1 = __builtin_amdgcn_cvt_pk_fp8_f32(b[2], b[3], p1, true);
  int2 pk = {p0, p1};
  // lane l covers orig bytes [l*8, l*8+8): t=l>>4 (128B block), s=(l>>2)&3, lk=l&3
  int poff = ((l >> 4) * 128) + ((l & 3) * 32) + (((l >> 2) & 3) * 8);
  *(int2*)(y8 + (size_t)row * H_ + poff) = pk;
}

// ---------------- prep: transpose+cast weights W[R][C] -> WT[C][R] bf16 ----------------
__global__ __launch_bounds__(256) void k_tw(const float* __restrict__ Wm,
                                            unsigned short* __restrict__ WT,
                                            int lgR, int C) {
  int i = blockIdx.x * 256 + threadIdx.x;     // over C*R outputs
  int R = 1 << lgR;
  int n = i >> lgR, k = i & (R - 1);
  WT[i] = f2bf(Wm[(size_t)k * C + n]);
}

// ---------------- prep: vt[b][h][s] = transpose(kn[b][s][h]) (bf16 -> bf16) ----------------
__global__ __launch_bounds__(256) void k_tvt(const unsigned short* __restrict__ kn,
                                             unsigned short* __restrict__ vt) {
  __shared__ unsigned short tile[64][72];
  int h0 = blockIdx.x * 64, s0 = blockIdx.y * 64, b = blockIdx.z;
  int t = threadIdx.x;
#pragma unroll
  for (int p = 0; p < 2; ++p) {
    int si = p * 32 + (t >> 3);
    int cj = (t & 7) * 8;
    short8 v = *(const short8*)(kn + ((size_t)(b * S2_ + s0 + si)) * H_ + h0 + cj);
#pragma unroll
    for (int x = 0; x < 8; ++x) tile[si][cj + x] = (unsigned short)v[x];
  }
  __syncthreads();
#pragma unroll
  for (int p = 0; p < 2; ++p) {
    int ho = p * 32 + (t >> 3);
    int sx = (t & 7) * 8;
    short8 o;
#pragma unroll
    for (int x = 0; x < 8; ++x) o[x] = (short)tile[sx + x][ho];
    *(short8*)(vt + ((size_t)(b * H_ + h0 + ho)) * S2_ + s0 + sx) = o;
  }
}

// ---------------- MFMA GEMM: 128-row tile, 4 waves, single-buf 32 KiB LDS ----
// Proven structure: stage -> vmcnt(0) -> barrier -> compute -> barrier; high
// blocks/CU residency + cross-block TLP hides staging latency (r3/r5: anything
// that cuts residency loses; r9: pass2 at 2 blk/CU was the slowest dispatch).
// FP8=1: A/B fp8 e4m3 in (s,lk)-permuted layout (see k_cast), BK=128; reads
// are short8 derefs (the pattern that emits ds_read_b128 conflict-free on the
// bf16 path) bit_cast to 2 longs -- r11's long2v deref was split by the
// compiler into 2x ds_read_b64 (bank = 2u mod 32, row-independent -> 4-way).
// SWZ: XCD swizzle; ON for pass2/FF (panel L2 locality), OFF for pass1.
// MODE 0: FF1 relu(acc+bias) bf16 | MODE 1: FF2 acc+bias bf16
// MODE 2: P=exp(acc*rq[m]*rk[n]-1)*mask bf16 (no rowsum: LN1 row-scale-inv)
// MODE 3: acc bf16
template <int MODE, int SWZ, int FP8>
__global__ __launch_bounds__(256, 2) void k_gemm(
    const void* __restrict__ A, const void* __restrict__ BT,
    const float* __restrict__ bias, const int* __restrict__ mask,
    const float* __restrict__ rq, const float* __restrict__ rk,
    void* __restrict__ out,
    int M, int N, int K, long sAbytes, long sBbytes, long sOut) {
  __shared__ char lA[16384];
  __shared__ char lB[16384];

  int bx, by, z;
  if (SWZ) {
    const int gx = gridDim.x, gy = gridDim.y;
    const int nwg = gx * gy * (int)gridDim.z;
    int orig = ((int)blockIdx.z * gy + (int)blockIdx.y) * gx + (int)blockIdx.x;
    int swzid = ((nwg & 7) == 0) ? ((orig & 7) * (nwg >> 3) + (orig >> 3)) : orig;
    z = swzid / (gx * gy);
    int rem = swzid - z * (gx * gy);
    by = rem / gx;
    bx = rem - by * gx;
  } else {
    bx = blockIdx.x; by = blockIdx.y; z = blockIdx.z;
  }

  const int w = threadIdx.x >> 6, l = threadIdx.x & 63;
  const int lr = l & 15, lk = l >> 4;
  const int m0 = by * 128, n0 = bx * 128;
  const int wm = (w >> 1) * 64, wn = (w & 1) * 64;

  // staging: chunk c=j*4+w covers rows 8c..8c+7 (128 B each); lane l covers
  // row 8c+(l>>3), 16 source bytes at col ((l&7)*16) ^ XOR-swizzle; dest linear.
  const size_t rowbytes = (size_t)K * (FP8 ? 1 : 2);
  const int srow = l >> 3;
  const int lswz = ((l & 7) * 16) ^ ((srow & 7) << 4);
  const char* pA = (const char*)A + (size_t)z * sAbytes + (size_t)(m0 + w * 8 + srow) * rowbytes + lswz;
  const char* pB = (const char*)BT + (size_t)z * sBbytes + (size_t)(n0 + w * 8 + srow) * rowbytes + lswz;
  const size_t rstep = rowbytes * 32;   // 32 rows per j-step

  f32x4 acc[4][4];
#pragma unroll
  for (int i = 0; i < 4; ++i)
#pragma unroll
    for (int j = 0; j < 4; ++j) acc[i][j] = (f32x4){0.f, 0.f, 0.f, 0.f};

  const int NT = K >> (FP8 ? 7 : 6);

#pragma unroll 1
  for (int t = 0; t < NT; ++t) {
    const size_t kb = (size_t)t * 128;   // 128 B per tile step in both dtypes
#pragma unroll
    for (int j = 0; j < 4; ++j) {
      gload_lds16(pA + j * rstep + kb, lA + (j * 4 + w) * 1024);
      gload_lds16(pB + j * rstep + kb, lB + (j * 4 + w) * 1024);
    }
    asm volatile("s_waitcnt vmcnt(0)" ::: "memory");
    __syncthreads();
    if (FP8) {
      // permuted layout: one 16B read at (lk*32 + s2*16) ^ swz holds the
      // s=2*s2 and s=2*s2+1 fragments; 16B unit x=(lk*2+s2)^(row&7) spans all
      // 8 slots per quarter-wave -> conflict-free iff emitted as ds_read_b128.
#pragma unroll
      for (int s2 = 0; s2 < 2; ++s2) {
        long2v af[4], bf[4];
#pragma unroll
        for (int mi = 0; mi < 4; ++mi) {
          int row = wm + mi * 16 + lr;
          short8 tmp = *(const short8*)(lA + row * 128 + ((lk * 32 + s2 * 16) ^ ((row & 7) << 4)));
          af[mi] = __builtin_bit_cast(long2v, tmp);
        }
#pragma unroll
        for (int ni = 0; ni < 4; ++ni) {
          int row = wn + ni * 16 + lr;
          short8 tmp = *(const short8*)(lB + row * 128 + ((lk * 32 + s2 * 16) ^ ((row & 7) << 4)));
          bf[ni] = __builtin_bit_cast(long2v, tmp);
        }
#pragma unroll
        for (int mi = 0; mi < 4; ++mi)
#pragma unroll
          for (int ni = 0; ni < 4; ++ni) {
            acc[mi][ni] = __builtin_amdgcn_mfma_f32_16x16x32_fp8_fp8(af[mi].x, bf[ni].x, acc[mi][ni], 0, 0, 0);
            acc[mi][ni] = __builtin_amdgcn_mfma_f32_16x16x32_fp8_fp8(af[mi].y, bf[ni].y, acc[mi][ni], 0, 0, 0);
          }
      }
    } else {
      const unsigned short* As = (const unsigned short*)lA;
      const unsigned short* Bs = (const unsigned short*)lB;
#pragma unroll
      for (int s = 0; s < 2; ++s) {
        short8 af[4], bf[4];
#pragma unroll
        for (int mi = 0; mi < 4; ++mi) {
          int row = wm + mi * 16 + lr;
          af[mi] = *(const short8*)(As + row * 64 + ((s * 32 + lk * 8) ^ ((row & 7) << 3)));
        }
#pragma unroll
        for (int ni = 0; ni < 4; ++ni) {
          int row = wn + ni * 16 + lr;
          bf[ni] = *(const short8*)(Bs + row * 64 + ((s * 32 + lk * 8) ^ ((row & 7) << 3)));
        }
#pragma unroll
        for (int mi = 0; mi < 4; ++mi)
#pragma unroll
          for (int ni = 0; ni < 4; ++ni)
            acc[mi][ni] = __builtin_amdgcn_mfma_f32_16x16x32_bf16(af[mi], bf[ni], acc[mi][ni], 0, 0, 0);
      }
    }
    __syncthreads();
  }

  if (MODE == 2) {
    float rqv[4][4], rkv[4], mv[4];
#pragma unroll
    for (int mi = 0; mi < 4; ++mi)
#pragma unroll
      for (int r = 0; r < 4; ++r)
        rqv[mi][r] = rq[(size_t)z * M + m0 + wm + mi * 16 + lk * 4 + r];
#pragma unroll
    for (int ni = 0; ni < 4; ++ni) {
      int gn = n0 + wn + ni * 16 + lr;
      rkv[ni] = rk[(size_t)z * N + gn];
      mv[ni] = (mask[(size_t)z * N + gn] != 0) ? 1.0f : 0.0f;
    }
#pragma unroll
    for (int mi = 0; mi < 4; ++mi)
#pragma unroll
      for (int ni = 0; ni < 4; ++ni) {
        int gn = n0 + wn + ni * 16 + lr;
#pragma unroll
        for (int r = 0; r < 4; ++r) {
          int gm = m0 + wm + mi * 16 + lk * 4 + r;
          float p = __expf(acc[mi][ni][r] * rqv[mi][r] * rkv[ni] - 1.0f) * mv[ni];
          ((unsigned short*)out)[(size_t)z * sOut + (size_t)gm * N + gn] = f2bf(p);
        }
      }
  } else if (MODE == 3) {
#pragma unroll
    for (int mi = 0; mi < 4; ++mi)
#pragma unroll
      for (int r = 0; r < 4; ++r) {
        int gm = m0 + wm + mi * 16 + lk * 4 + r;
#pragma unroll
        for (int ni = 0; ni < 4; ++ni) {
          int gn = n0 + wn + ni * 16 + lr;
          ((unsigned short*)out)[(size_t)z * sOut + (size_t)gm * N + gn] = f2bf(acc[mi][ni][r]);
        }
      }
  } else {
#pragma unroll
    for (int mi = 0; mi < 4; ++mi)
#pragma unroll
      for (int ni = 0; ni < 4; ++ni) {
        int gn = n0 + wn + ni * 16 + lr;
        float bs = bias[gn];
#pragma unroll
        for (int r = 0; r < 4; ++r) {
          int gm = m0 + wm + mi * 16 + lk * 4 + r;
          float v = acc[mi][ni][r] + bs;
          if (MODE == 0) v = fmaxf(v, 0.f);
          ((unsigned short*)out)[(size_t)gm * N + gn] = f2bf(v);
        }
      }
  }
}

// ---------------- LN1: nattn = LN(O)*g+b (bf16); O unnormalized (LN scale-inv) ----
__global__ __launch_bounds__(256) void k_ln1(const unsigned short* __restrict__ O,
                                             const float* __restrict__ g,
                                             const float* __restrict__ bvec,
                                             unsigned short* __restrict__ nattn) {
  int row = blockIdx.x * 4 + (threadIdx.x >> 6);
  int l = threadIdx.x & 63;
  size_t base = (size_t)row * H_ + l * 8;
  short8 ov = *(const short8*)(O + base);
  float x[8];
#pragma unroll
  for (int i = 0; i < 8; ++i) x[i] = bf2f((unsigned short)ov[i]);
  float s = 0.f, q = 0.f;
#pragma unroll
  for (int i = 0; i < 8; ++i) { s += x[i]; q += x[i] * x[i]; }
#pragma unroll
  for (int m = 1; m < 64; m <<= 1) { s += __shfl_xor(s, m); q += __shfl_xor(q, m); }
  float mean = s * (1.f / 512.f);
  float var = q * (1.f / 512.f) - mean * mean;
  float rstd = rsqrtf(var + 1e-6f);
  f32x4 g0 = *(const f32x4*)(g + l * 8), g1v = *(const f32x4*)(g + l * 8 + 4);
  f32x4 b0 = *(const f32x4*)(bvec + l * 8), b1v = *(const f32x4*)(bvec + l * 8 + 4);
  short8 no;
#pragma unroll
  for (int i = 0; i < 4; ++i) {
    no[i]     = (short)f2bf((x[i] - mean) * rstd * g0[i] + b0[i]);
    no[4 + i] = (short)f2bf((x[4 + i] - mean) * rstd * g1v[i] + b1v[i]);
  }
  *(short8*)(nattn + base) = no;
}

// ---------------- LN2(ff bf16) + nattn + text1 -> out ----------------
__global__ __launch_bounds__(256) void k_ln2(const unsigned short* __restrict__ ff,
                                             const unsigned short* __restrict__ nattn,
                                             const float* __restrict__ text1,
                                             const float* __restrict__ g2,
                                             const float* __restrict__ bb2,
                                             float* __restrict__ out) {
  int row = blockIdx.x * 4 + (threadIdx.x >> 6);
  int l = threadIdx.x & 63;
  size_t base = (size_t)row * H_ + l * 8;
  short8 fv = *(const short8*)(ff + base);
  float x[8];
#pragma unroll
  for (int i = 0; i < 8; ++i) x[i] = bf2f((unsigned short)fv[i]);
  float s = 0.f, q = 0.f;
#pragma unroll
  for (int i = 0; i < 8; ++i) { s += x[i]; q += x[i] * x[i]; }
#pragma unroll
  for (int m = 1; m < 64; m <<= 1) { s += __shfl_xor(s, m); q += __shfl_xor(q, m); }
  float mean = s * (1.f / 512.f);
  float var = q * (1.f / 512.f) - mean * mean;
  float rstd = rsqrtf(var + 1e-6f);
  f32x4 g0 = *(const f32x4*)(g2 + l * 8), g1v = *(const f32x4*)(g2 + l * 8 + 4);
  f32x4 b0 = *(const f32x4*)(bb2 + l * 8), b1v = *(const f32x4*)(bb2 + l * 8 + 4);
  short8 nv = *(const short8*)(nattn + base);
  f32x4 t0 = *(const f32x4*)(text1 + base), t1 = *(const f32x4*)(text1 + base + 4);
  f32x4 o0, o1;
#pragma unroll
  for (int i = 0; i < 4; ++i) {
    o0[i] = (x[i] - mean) * rstd * g0[i] + b0[i] + bf2f((unsigned short)nv[i]) + t0[i];
    o1[i] = (x[4 + i] - mean) * rstd * g1v[i] + b1v[i] + bf2f((unsigned short)nv[4 + i]) + t1[i];
  }
  *(f32x4*)(out + base) = o0;
  *(f32x4*)(out + base + 4) = o1;
}

extern "C" void kernel_launch(void* const* d_in, const int* in_sizes, int n_in,
                              void* d_out, int out_size, void* d_ws, size_t ws_size,
                              hipStream_t stream) {
  const float* text1 = (const float*)d_in[0];
  const float* text2 = (const float*)d_in[1];
  // d_in[2] = text1_mask (unused by reference output)
  const int* mask2 = (const int*)d_in[3];
  const float* W1 = (const float*)d_in[4];
  const float* b1 = (const float*)d_in[5];
  const float* W2 = (const float*)d_in[6];
  const float* b2 = (const float*)d_in[7];
  const float* g1 = (const float*)d_in[8];
  const float* bb1 = (const float*)d_in[9];
  const float* g2 = (const float*)d_in[10];
  const float* bb2 = (const float*)d_in[11];

  const size_t MiB = 1024ull * 1024ull;
  char* ws = (char*)d_ws;
  // ---- layout (max offset 196 MiB) ----
  unsigned short* W1T   = (unsigned short*)(ws + 0 * MiB);          // 1 MiB
  unsigned short* W2T   = (unsigned short*)(ws + 1 * MiB);          // 1 MiB
  float*          rq    = (float*)(ws + 2 * MiB);                   // 128 KiB
  float*          rk    = (float*)(ws + 2 * MiB + 256 * 1024);      // 128 KiB
  unsigned char*  qn8   = (unsigned char*)(ws + 4 * MiB);     // 16 MiB [4,20)
  unsigned char*  kn8   = (unsigned char*)(ws + 20 * MiB);    // 16 MiB [20,36)
  unsigned short* kn    = (unsigned short*)(ws + 36 * MiB);   // 32 MiB [36,68): dead after k_tvt
  unsigned short* vt    = (unsigned short*)(ws + 164 * MiB);  // 32 MiB [164,196): dead after pass2
  unsigned short* P     = (unsigned short*)(ws + 36 * MiB);   // 128 MiB [36,164) over kn (dead);
                                                              //   all 16 batches, dead after pass2
  unsigned short* O     = (unsigned short*)(ws + 4 * MiB);    // 32 MiB [4,36) over qn8+kn8 (dead
                                                              //   after pass1; pass2 runs later)
  // aliases (stream-order lifetimes; each span checked against later readers):
  unsigned short* nattn = (unsigned short*)(ws + 100 * MiB);  // [100,132) over P-mid (dead after
                                                              //   pass2); live LN1 -> LN2; nothing
                                                              //   writes [100,132) in between (FF1
                                                              //   -> [132,196), FF2 -> [36,68)).
  unsigned short* hbuf  = (unsigned short*)(ws + 132 * MiB);  // [132,196) over P-upper + vt (both
                                                              //   dead after pass2)
  unsigned short* ffb   = (unsigned short*)(ws + 36 * MiB);   // [36,68) over P-lower (dead); NOT
                                                              //   overlapping nattn (round-4 bug)
  float* outp = (float*)d_out;

  k_cast<0><<<dim3(B_ * S1_ / 4), 256, 0, stream>>>(text1, nullptr, qn8, rq);
  k_cast<1><<<dim3(B_ * S2_ / 4), 256, 0, stream>>>(text2, kn, kn8, rk);
  k_tw<<<dim3(512 * 1024 / 256), 256, 0, stream>>>(W1, W1T, 9, 1024);
  k_tw<<<dim3(512 * 1024 / 256), 256, 0, stream>>>(W2, W2T, 10, 512);
  k_tvt<<<dim3(H_ / 64, S2_ / 64, B_), 256, 0, stream>>>(kn, vt);

  // pass1 (fp8 permuted, BK=128), all 16 batches: P = exp((q8@k8^T)*rq*rk - 1)*mask [SWZ=0]
  k_gemm<2, 0, 1><<<dim3(S2_ / 128, S1_ / 128, B_), 256, 0, stream>>>(
      qn8, kn8, nullptr, mask2, rq, rk,
      P, S1_, S2_, H_, (long)S1_ * H_, (long)S2_ * H_, (long)S1_ * S2_);
  // pass2 (bf16), all 16 batches: O = P @ V (unnormalized; LN1 washes row scale)
  // grid 4x16x16 = 1024 blocks = 4 blk/CU (r9: 512 blocks = 2/CU was the bottleneck)
  k_gemm<3, 1, 0><<<dim3(H_ / 128, S1_ / 128, B_), 256, 0, stream>>>(
      P, vt, nullptr, nullptr, nullptr, nullptr,
      O, S1_, H_, S2_, (long)S1_ * S2_ * 2, (long)H_ * S2_ * 2, (long)S1_ * H_);

  k_ln1<<<dim3(B_ * S1_ / 4), 256, 0, stream>>>(O, g1, bb1, nattn);
  k_gemm<0, 1, 0><<<dim3(1024 / 128, 32768 / 128, 1), 256, 0, stream>>>(
      nattn, W1T, b1, nullptr, nullptr, nullptr, hbuf, 32768, 1024, 512, 0, 0, 0);
  k_gemm<1, 1, 0><<<dim3(512 / 128, 32768 / 128, 1), 256, 0, stream>>>(
      hbuf, W2T, b2, nullptr, nullptr, nullptr, ffb, 32768, 512, 1024, 0, 0, 0);
  k_ln2<<<dim3(32768 / 4), 256, 0, stream>>>(ffb, nattn, text1, g2, bb2, outp);
}